// Round 1
// baseline (7820.024 us; speedup 1.0000x reference)
//
#include <hip/hip_runtime.h>
#include <math.h>

#define DIM 1024
#define FFN_DIM 4096
#define HEADS 8
#define HD 128
#define BB 2
#define LL 2048
#define NROWS (BB*LL)   // 4096

// ---------------- LayerNorm (one block per row of 1024) ----------------
__global__ __launch_bounds__(256) void ln_kernel(
    const float* __restrict__ x, const float* __restrict__ w,
    const float* __restrict__ b, float* __restrict__ out)
{
    int row = blockIdx.x;
    int tid = threadIdx.x;
    const float* xr = x + (size_t)row * DIM;
    float4 v = *(const float4*)(xr + tid * 4);
    float s  = v.x + v.y + v.z + v.w;
    float ss = v.x*v.x + v.y*v.y + v.z*v.z + v.w*v.w;
    #pragma unroll
    for (int o = 32; o > 0; o >>= 1) { s += __shfl_down(s, o); ss += __shfl_down(ss, o); }
    __shared__ float red[10];
    int wid = tid >> 6;
    if ((tid & 63) == 0) { red[wid] = s; red[4 + wid] = ss; }
    __syncthreads();
    if (tid == 0) {
        float t  = red[0] + red[1] + red[2] + red[3];
        float t2 = red[4] + red[5] + red[6] + red[7];
        float mu  = t * (1.f / DIM);
        float var = t2 * (1.f / DIM) - mu * mu;
        red[8] = mu; red[9] = rsqrtf(var + 1e-5f);
    }
    __syncthreads();
    float mu = red[8], rs = red[9];
    float4 wv = *(const float4*)(w + tid * 4);
    float4 bv = *(const float4*)(b + tid * 4);
    float4 o;
    o.x = (v.x - mu) * rs * wv.x + bv.x;
    o.y = (v.y - mu) * rs * wv.y + bv.y;
    o.z = (v.z - mu) * rs * wv.z + bv.z;
    o.w = (v.w - mu) * rs * wv.w + bv.w;
    *(float4*)(out + (size_t)row * DIM + tid * 4) = o;
}

// ---------------- Wq/Wk/Wv (h,d,e) -> (d, h*128+e) ----------------
__global__ void transpose_w(const float* __restrict__ in, float* __restrict__ out)
{
    int e = threadIdx.x;       // 0..127
    int d = blockIdx.x;        // 0..1023
    int h = blockIdx.y;        // 0..7
    out[(size_t)d * DIM + h * HD + e] = in[((size_t)h * DIM + d) * HD + e];
}

// ---------------- fp32 tiled GEMM: C = A(N,K) @ B(K,M) ----------------
// EPI: 0 none, 1 bias+gelu(exact), 2 bias+residual, 3 residual
#define BM 128
#define BN 64
#define BK 16
template<int EPI>
__global__ __launch_bounds__(256) void gemm_f32(
    const float* __restrict__ A, const float* __restrict__ B,
    float* __restrict__ C, const float* __restrict__ bias,
    const float* __restrict__ R, int N, int K, int M)
{
    __shared__ float As[BK][BM + 4];
    __shared__ float Bs[BK][BN + 4];
    int tid = threadIdx.x;
    int bm = blockIdx.y * BM;
    int bn = blockIdx.x * BN;
    int tr = tid >> 4;              // 0..15 -> 8 rows each
    int tc = tid & 15;              // 0..15 -> 4 cols each
    int ar = tid >> 2;              // 0..63
    int ac = (tid & 3) * 4;
    int br = tid >> 4;              // 0..15
    int bc = (tid & 15) * 4;
    float acc[8][4] = {};
    for (int k0 = 0; k0 < K; k0 += BK) {
        float4 a0 = *(const float4*)(A + (size_t)(bm + ar) * K + k0 + ac);
        float4 a1 = *(const float4*)(A + (size_t)(bm + ar + 64) * K + k0 + ac);
        float4 b0 = *(const float4*)(B + (size_t)(k0 + br) * M + bn + bc);
        __syncthreads();   // previous tile's compute done before overwrite
        As[ac + 0][ar] = a0.x; As[ac + 1][ar] = a0.y; As[ac + 2][ar] = a0.z; As[ac + 3][ar] = a0.w;
        As[ac + 0][ar + 64] = a1.x; As[ac + 1][ar + 64] = a1.y; As[ac + 2][ar + 64] = a1.z; As[ac + 3][ar + 64] = a1.w;
        *(float4*)(&Bs[br][bc]) = b0;
        __syncthreads();
        #pragma unroll
        for (int kk = 0; kk < BK; ++kk) {
            float4 af0 = *(const float4*)(&As[kk][tr * 8]);
            float4 af1 = *(const float4*)(&As[kk][tr * 8 + 4]);
            float4 bf  = *(const float4*)(&Bs[kk][tc * 4]);
            float a[8] = {af0.x, af0.y, af0.z, af0.w, af1.x, af1.y, af1.z, af1.w};
            float bb[4] = {bf.x, bf.y, bf.z, bf.w};
            #pragma unroll
            for (int i = 0; i < 8; ++i)
                #pragma unroll
                for (int j = 0; j < 4; ++j)
                    acc[i][j] += a[i] * bb[j];
        }
    }
    #pragma unroll
    for (int i = 0; i < 8; ++i) {
        int row = bm + tr * 8 + i;
        size_t off = (size_t)row * M + bn + tc * 4;
        float4 o = {acc[i][0], acc[i][1], acc[i][2], acc[i][3]};
        if constexpr (EPI == 1) {
            float4 bi = *(const float4*)(bias + bn + tc * 4);
            o.x += bi.x; o.y += bi.y; o.z += bi.z; o.w += bi.w;
            o.x = 0.5f * o.x * (1.f + erff(o.x * 0.70710678118654752f));
            o.y = 0.5f * o.y * (1.f + erff(o.y * 0.70710678118654752f));
            o.z = 0.5f * o.z * (1.f + erff(o.z * 0.70710678118654752f));
            o.w = 0.5f * o.w * (1.f + erff(o.w * 0.70710678118654752f));
        } else if constexpr (EPI == 2) {
            float4 bi = *(const float4*)(bias + bn + tc * 4);
            float4 r  = *(const float4*)(R + off);
            o.x += bi.x + r.x; o.y += bi.y + r.y; o.z += bi.z + r.z; o.w += bi.w + r.w;
        } else if constexpr (EPI == 3) {
            float4 r = *(const float4*)(R + off);
            o.x += r.x; o.y += r.y; o.z += r.z; o.w += r.w;
        }
        *(float4*)(C + off) = o;
    }
}

// ---------------- xPos rotary, in-place on (N,1024) rows ----------------
__global__ __launch_bounds__(256) void xpos_kernel(float* __restrict__ X, int downscale)
{
    int idx = blockIdx.x * 256 + threadIdx.x;   // [0, NROWS*512)
    int n = idx >> 9;
    int c = idx & 511;          // pair index within row
    int j = c & 63;             // pair index within head
    int l = n & (LL - 1);       // sequence position
    float pos = (float)l;
    float bs = (2.f * (float)j + 0.4f * (float)HD) / (1.4f * (float)HD);
    float sc = powf(bs, pos * (1.f / 512.f));
    float s = downscale ? (1.f / sc) : sc;
    float invf = powf(10000.f, -(float)j * (1.f / 64.f));
    float ang = pos * invf;
    float sn, cn;
    sincosf(ang, &sn, &cn);
    float2 q = *(float2*)(X + (size_t)n * DIM + c * 2);
    float cs = cn * s, ssn = sn * s;
    float2 o;
    o.x = q.x * cs - q.y * ssn;
    o.y = q.y * cs + q.x * ssn;
    *(float2*)(X + (size_t)n * DIM + c * 2) = o;
}

// ---------------- retention: Y = (QK^T * decay) V, flash-style ----------------
#define RT 32
#define KSTR 132   // padded LDS row stride
__global__ __launch_bounds__(256) void retention_kernel(
    const float* __restrict__ Q, const float* __restrict__ K,
    const float* __restrict__ V, float* __restrict__ Y)
{
    int lt = blockIdx.x;    // l-tile 0..63
    int h  = blockIdx.y;
    int b  = blockIdx.z;
    int tid = threadIdx.x;
    __shared__ float Ks[RT * KSTR];
    __shared__ float Vs[RT * KSTR];
    int a  = tid >> 3;           // row within tile 0..31
    int eo = (tid & 7) * 16;     // this lane's 16-wide e/v slice
    int l  = lt * RT + a;
    const float* qrow = Q + ((size_t)(b * LL + l)) * DIM + h * HD + eo;
    float qreg[16];
    #pragma unroll
    for (int i = 0; i < 16; i += 4) {
        float4 t = *(const float4*)(qrow + i);
        qreg[i] = t.x; qreg[i+1] = t.y; qreg[i+2] = t.z; qreg[i+3] = t.w;
    }
    float yacc[16] = {};
    const float lg_lo = -3.4657359027997265f;   // log(1/32)
    const float lg_hi = -6.2383246250395075f;   // log(1/512)
    float gamma = 1.f - expf(lg_lo + (lg_hi - lg_lo) * ((float)h / 7.f));
    float logg = logf(gamma);
    for (int mt = 0; mt <= lt; ++mt) {
        float4 kreg[4], vreg[4];
        #pragma unroll
        for (int i = 0; i < 4; ++i) {
            int f = tid + i * 256;
            int r = f >> 5;
            int c4 = (f & 31) << 2;
            size_t g = ((size_t)(b * LL + mt * RT + r)) * DIM + h * HD + c4;
            kreg[i] = *(const float4*)(K + g);
            vreg[i] = *(const float4*)(V + g);
        }
        __syncthreads();
        #pragma unroll
        for (int i = 0; i < 4; ++i) {
            int f = tid + i * 256;
            int r = f >> 5;
            int c4 = (f & 31) << 2;
            *(float4*)(&Ks[r * KSTR + c4]) = kreg[i];
            *(float4*)(&Vs[r * KSTR + c4]) = vreg[i];
        }
        __syncthreads();
        // scores: S[a][c] = Q_l . K_m  (8-lane partial dots + shuffle reduce)
        float sreg[32];
        #pragma unroll
        for (int cc = 0; cc < 32; ++cc) {
            int c = (cc + a) & 31;   // stagger c per row-group to spread LDS banks
            const float* kr = &Ks[c * KSTR + eo];
            float p = 0.f;
            #pragma unroll
            for (int i = 0; i < 16; ++i) p += qreg[i] * kr[i];
            p += __shfl_xor(p, 1);
            p += __shfl_xor(p, 2);
            p += __shfl_xor(p, 4);
            sreg[cc] = p;
        }
        // decay-weighted accumulation into Y
        int m0 = mt * RT;
        #pragma unroll
        for (int cc = 0; cc < 32; ++cc) {
            int c = (cc + a) & 31;
            int d = l - (m0 + c);
            float wdec = (d >= 0) ? expf(logg * (float)d) : 0.f;
            float sv = sreg[cc] * wdec;
            const float* vr = &Vs[c * KSTR + eo];
            #pragma unroll
            for (int i = 0; i < 16; ++i) yacc[i] += sv * vr[i];
        }
    }
    float* yrow = Y + ((size_t)(b * LL + l)) * DIM + h * HD + eo;
    #pragma unroll
    for (int i = 0; i < 16; i += 4) {
        float4 t = {yacc[i], yacc[i+1], yacc[i+2], yacc[i+3]};
        *(float4*)(yrow + i) = t;
    }
}

// ---------------- groupnorm (per (n,h) over 128) * gate, in-place on Y ----------------
__global__ __launch_bounds__(256) void gn_gate_kernel(
    float* __restrict__ Y, const float* __restrict__ G,
    const float* __restrict__ w, const float* __restrict__ b)
{
    int tid = threadIdx.x;
    int wid = tid >> 6, lane = tid & 63;
    int grp = blockIdx.x * 4 + wid;     // [0, N*H)
    int n = grp >> 3, h = grp & 7;
    size_t base = (size_t)n * DIM + h * HD + lane * 2;
    float2 y = *(float2*)(Y + base);
    float s = y.x + y.y, ss = y.x * y.x + y.y * y.y;
    #pragma unroll
    for (int o = 32; o > 0; o >>= 1) { s += __shfl_down(s, o); ss += __shfl_down(ss, o); }
    s = __shfl(s, 0); ss = __shfl(ss, 0);
    float mu  = s * (1.f / HD);
    float var = ss * (1.f / HD) - mu * mu;
    float rs  = rsqrtf(var + 1e-5f);
    float2 wv = *(const float2*)(w + h * HD + lane * 2);
    float2 bv = *(const float2*)(b + h * HD + lane * 2);
    float2 gv = *(const float2*)(G + base);
    float g0 = gv.x / (1.f + expf(-gv.x));   // g*sigmoid(g)
    float g1 = gv.y / (1.f + expf(-gv.y));
    float2 o;
    o.x = ((y.x - mu) * rs * wv.x + bv.x) * g0;
    o.y = ((y.y - mu) * rs * wv.y + bv.y) * g1;
    *(float2*)(Y + base) = o;
}

extern "C" void kernel_launch(void* const* d_in, const int* in_sizes, int n_in,
                              void* d_out, int out_size, void* d_ws, size_t ws_size,
                              hipStream_t stream)
{
    const float* X0   = (const float*)d_in[0];
    const float* Wq   = (const float*)d_in[1];
    const float* Wk   = (const float*)d_in[2];
    const float* Wv   = (const float*)d_in[3];
    const float* WG   = (const float*)d_in[4];
    const float* WO   = (const float*)d_in[5];
    const float* gnw  = (const float*)d_in[6];
    const float* gnb  = (const float*)d_in[7];
    const float* ln1w = (const float*)d_in[8];
    const float* ln1b = (const float*)d_in[9];
    const float* ln2w = (const float*)d_in[10];
    const float* ln2b = (const float*)d_in[11];
    const float* fw1  = (const float*)d_in[12];
    const float* fb1  = (const float*)d_in[13];
    const float* fw2  = (const float*)d_in[14];
    const float* fb2  = (const float*)d_in[15];

    float* ws = (float*)d_ws;
    const size_t U = (size_t)NROWS * DIM;    // 4,194,304 floats = 16 MB
    float* sXn = ws + 0 * U;    // LN1 out, later Ylayer (attn+resid)
    float* sQ  = ws + 1 * U;    // Q, later LN2 out (h)
    float* sK  = ws + 2 * U;    // K, later FFN hidden (chunk) low half
    float* sV  = ws + 3 * U;    // V, later FFN hidden (chunk) high half
    float* sY  = ws + 4 * U;    // retention out -> gated (in-place)
    float* sG  = ws + 5 * U;    // gate input; first 12MB doubles as Wq/Wk/Wv transposed
    float* sX  = ws + 6 * U;    // X between layers
    float* sH1 = sK;            // 2048 x 4096 = 2 units
    float* sWt = sG;
    // total workspace: 7 * 16 MB = 112 MB

    for (int i = 0; i < 2; ++i) {
        const float* Xin = (i == 0) ? X0 : sX;
        float* Xout = (i == 1) ? (float*)d_out : sX;

        // LN1
        ln_kernel<<<NROWS, 256, 0, stream>>>(Xin, ln1w + i * DIM, ln1b + i * DIM, sXn);
        // transpose projection weights (h,d,e)->(d,h*e)
        dim3 tg(DIM, HEADS);
        transpose_w<<<tg, HD, 0, stream>>>(Wq + (size_t)i * HEADS * DIM * HD, sWt + 0 * 1048576);
        transpose_w<<<tg, HD, 0, stream>>>(Wk + (size_t)i * HEADS * DIM * HD, sWt + 1 * 1048576);
        transpose_w<<<tg, HD, 0, stream>>>(Wv + (size_t)i * HEADS * DIM * HD, sWt + 2 * 1048576);
        // projections (Wt must be read before gemm G overwrites sG)
        dim3 g1(DIM / BN, NROWS / BM);   // (16, 32)
        gemm_f32<0><<<g1, 256, 0, stream>>>(sXn, sWt + 0 * 1048576, sQ, nullptr, nullptr, NROWS, DIM, DIM);
        gemm_f32<0><<<g1, 256, 0, stream>>>(sXn, sWt + 1 * 1048576, sK, nullptr, nullptr, NROWS, DIM, DIM);
        gemm_f32<0><<<g1, 256, 0, stream>>>(sXn, sWt + 2 * 1048576, sV, nullptr, nullptr, NROWS, DIM, DIM);
        gemm_f32<0><<<g1, 256, 0, stream>>>(sXn, WG + (size_t)i * DIM * DIM, sG, nullptr, nullptr, NROWS, DIM, DIM);
        // xPos
        xpos_kernel<<<NROWS * 512 / 256, 256, 0, stream>>>(sQ, 0);
        xpos_kernel<<<NROWS * 512 / 256, 256, 0, stream>>>(sK, 1);
        // retention
        dim3 rg(LL / RT, HEADS, BB);
        retention_kernel<<<rg, 256, 0, stream>>>(sQ, sK, sV, sY);
        // groupnorm + swish gate (in place on sY)
        gn_gate_kernel<<<NROWS * HEADS / 4, 256, 0, stream>>>(sY, sG, gnw + i * DIM, gnb + i * DIM);
        // W_O + residual -> Ylayer (sXn)
        gemm_f32<3><<<g1, 256, 0, stream>>>(sY, WO + (size_t)i * DIM * DIM, sXn, nullptr, Xin, NROWS, DIM, DIM);
        // LN2 -> sQ
        ln_kernel<<<NROWS, 256, 0, stream>>>(sXn, ln2w + i * DIM, ln2b + i * DIM, sQ);
        // FFN in 2 row-chunks of 2048 (hidden reuses freed K/V space)
        for (int rc = 0; rc < 2; ++rc) {
            const float* hA = sQ + (size_t)rc * 2048 * DIM;
            dim3 gf1(FFN_DIM / BN, 2048 / BM);   // (64, 16)
            gemm_f32<1><<<gf1, 256, 0, stream>>>(hA, fw1 + (size_t)i * DIM * FFN_DIM, sH1,
                                                 fb1 + i * FFN_DIM, nullptr, 2048, DIM, FFN_DIM);
            dim3 gf2(DIM / BN, 2048 / BM);       // (16, 16)
            gemm_f32<2><<<gf2, 256, 0, stream>>>(sH1, fw2 + (size_t)i * FFN_DIM * DIM,
                                                 Xout + (size_t)rc * 2048 * DIM,
                                                 fb2 + i * DIM, sXn + (size_t)rc * 2048 * DIM,
                                                 2048, FFN_DIM, DIM);
        }
    }
}

// Round 2
// 3944.436 us; speedup vs baseline: 1.9825x; 1.9825x over previous
//
#include <hip/hip_runtime.h>
#include <math.h>

#define DIM 1024
#define FFN_DIM 4096
#define HEADS 8
#define HD 128
#define BB 2
#define LL 2048
#define NROWS (BB*LL)   // 4096

typedef __attribute__((ext_vector_type(8))) short bf16x8;
typedef __attribute__((ext_vector_type(4))) float f32x4;

__device__ inline short f2bf(float f) {
    unsigned u = __builtin_bit_cast(unsigned, f);
    unsigned r = (u + 0x7FFFu + ((u >> 16) & 1u)) >> 16;
    return (short)r;
}

// ---------------- LayerNorm (one block per row of 1024) ----------------
__global__ __launch_bounds__(256) void ln_kernel(
    const float* __restrict__ x, const float* __restrict__ w,
    const float* __restrict__ b, float* __restrict__ out)
{
    int row = blockIdx.x;
    int tid = threadIdx.x;
    const float* xr = x + (size_t)row * DIM;
    float4 v = *(const float4*)(xr + tid * 4);
    float s  = v.x + v.y + v.z + v.w;
    float ss = v.x*v.x + v.y*v.y + v.z*v.z + v.w*v.w;
    #pragma unroll
    for (int o = 32; o > 0; o >>= 1) { s += __shfl_down(s, o); ss += __shfl_down(ss, o); }
    __shared__ float red[10];
    int wid = tid >> 6;
    if ((tid & 63) == 0) { red[wid] = s; red[4 + wid] = ss; }
    __syncthreads();
    if (tid == 0) {
        float t  = red[0] + red[1] + red[2] + red[3];
        float t2 = red[4] + red[5] + red[6] + red[7];
        float mu  = t * (1.f / DIM);
        float var = t2 * (1.f / DIM) - mu * mu;
        red[8] = mu; red[9] = rsqrtf(var + 1e-5f);
    }
    __syncthreads();
    float mu = red[8], rs = red[9];
    float4 wv = *(const float4*)(w + tid * 4);
    float4 bv = *(const float4*)(b + tid * 4);
    float4 o;
    o.x = (v.x - mu) * rs * wv.x + bv.x;
    o.y = (v.y - mu) * rs * wv.y + bv.y;
    o.z = (v.z - mu) * rs * wv.z + bv.z;
    o.w = (v.w - mu) * rs * wv.w + bv.w;
    *(float4*)(out + (size_t)row * DIM + tid * 4) = o;
}

// ---------------- Wq/Wk/Wv (h,d,e) -> (d, h*128+e) ----------------
__global__ void transpose_w(const float* __restrict__ in, float* __restrict__ out)
{
    int e = threadIdx.x;       // 0..127
    int d = blockIdx.x;        // 0..1023
    int h = blockIdx.y;        // 0..7
    out[(size_t)d * DIM + h * HD + e] = in[((size_t)h * DIM + d) * HD + e];
}

// ---------------- fp32 tiled GEMM: C = A(N,K) @ B(K,M) ----------------
// EPI: 0 none, 1 bias+gelu(exact), 2 bias+residual, 3 residual
#define BM 128
#define BN 64
#define BK 16
template<int EPI>
__global__ __launch_bounds__(256) void gemm_f32(
    const float* __restrict__ A, const float* __restrict__ B,
    float* __restrict__ C, const float* __restrict__ bias,
    const float* __restrict__ R, int N, int K, int M)
{
    __shared__ float As[BK][BM + 4];
    __shared__ float Bs[BK][BN + 4];
    int tid = threadIdx.x;
    int bm = blockIdx.y * BM;
    int bn = blockIdx.x * BN;
    int tr = tid >> 4;              // 0..15 -> 8 rows each
    int tc = tid & 15;              // 0..15 -> 4 cols each
    int ar = tid >> 2;              // 0..63
    int ac = (tid & 3) * 4;
    int br = tid >> 4;              // 0..15
    int bc = (tid & 15) * 4;
    float acc[8][4] = {};
    for (int k0 = 0; k0 < K; k0 += BK) {
        float4 a0 = *(const float4*)(A + (size_t)(bm + ar) * K + k0 + ac);
        float4 a1 = *(const float4*)(A + (size_t)(bm + ar + 64) * K + k0 + ac);
        float4 b0 = *(const float4*)(B + (size_t)(k0 + br) * M + bn + bc);
        __syncthreads();   // previous tile's compute done before overwrite
        As[ac + 0][ar] = a0.x; As[ac + 1][ar] = a0.y; As[ac + 2][ar] = a0.z; As[ac + 3][ar] = a0.w;
        As[ac + 0][ar + 64] = a1.x; As[ac + 1][ar + 64] = a1.y; As[ac + 2][ar + 64] = a1.z; As[ac + 3][ar + 64] = a1.w;
        *(float4*)(&Bs[br][bc]) = b0;
        __syncthreads();
        #pragma unroll
        for (int kk = 0; kk < BK; ++kk) {
            float4 af0 = *(const float4*)(&As[kk][tr * 8]);
            float4 af1 = *(const float4*)(&As[kk][tr * 8 + 4]);
            float4 bf  = *(const float4*)(&Bs[kk][tc * 4]);
            float a[8] = {af0.x, af0.y, af0.z, af0.w, af1.x, af1.y, af1.z, af1.w};
            float bb[4] = {bf.x, bf.y, bf.z, bf.w};
            #pragma unroll
            for (int i = 0; i < 8; ++i)
                #pragma unroll
                for (int j = 0; j < 4; ++j)
                    acc[i][j] += a[i] * bb[j];
        }
    }
    #pragma unroll
    for (int i = 0; i < 8; ++i) {
        int row = bm + tr * 8 + i;
        size_t off = (size_t)row * M + bn + tc * 4;
        float4 o = {acc[i][0], acc[i][1], acc[i][2], acc[i][3]};
        if constexpr (EPI == 1) {
            float4 bi = *(const float4*)(bias + bn + tc * 4);
            o.x += bi.x; o.y += bi.y; o.z += bi.z; o.w += bi.w;
            o.x = 0.5f * o.x * (1.f + erff(o.x * 0.70710678118654752f));
            o.y = 0.5f * o.y * (1.f + erff(o.y * 0.70710678118654752f));
            o.z = 0.5f * o.z * (1.f + erff(o.z * 0.70710678118654752f));
            o.w = 0.5f * o.w * (1.f + erff(o.w * 0.70710678118654752f));
        } else if constexpr (EPI == 2) {
            float4 bi = *(const float4*)(bias + bn + tc * 4);
            float4 r  = *(const float4*)(R + off);
            o.x += bi.x + r.x; o.y += bi.y + r.y; o.z += bi.z + r.z; o.w += bi.w + r.w;
        } else if constexpr (EPI == 3) {
            float4 r = *(const float4*)(R + off);
            o.x += r.x; o.y += r.y; o.z += r.z; o.w += r.w;
        }
        *(float4*)(C + off) = o;
    }
}

// ---------------- xPos rotary, in-place on (N,1024) rows ----------------
__global__ __launch_bounds__(256) void xpos_kernel(float* __restrict__ X, int downscale)
{
    int idx = blockIdx.x * 256 + threadIdx.x;   // [0, NROWS*512)
    int n = idx >> 9;
    int c = idx & 511;          // pair index within row
    int j = c & 63;             // pair index within head
    int l = n & (LL - 1);       // sequence position
    float pos = (float)l;
    float bs = (2.f * (float)j + 0.4f * (float)HD) / (1.4f * (float)HD);
    float sc = powf(bs, pos * (1.f / 512.f));
    float s = downscale ? (1.f / sc) : sc;
    float invf = powf(10000.f, -(float)j * (1.f / 64.f));
    float ang = pos * invf;
    float sn, cn;
    sincosf(ang, &sn, &cn);
    float2 q = *(float2*)(X + (size_t)n * DIM + c * 2);
    float cs = cn * s, ssn = sn * s;
    float2 o;
    o.x = q.x * cs - q.y * ssn;
    o.y = q.y * cs + q.x * ssn;
    *(float2*)(X + (size_t)n * DIM + c * 2) = o;
}

// ---------------- retention via bf16 MFMA, flash-style ----------------
// Block: (pairIdx, h, b). Processes q-tiles jt = pairIdx and 31-pairIdx (64 rows
// each; 4 waves x 16 rows). KV tiles of 32 rows staged in LDS (K row-major bf16,
// V transposed). Decay applied in C-layout via factored gamma powers; P transposed
// to A-layout through per-wave LDS buffer (m120-verified transform).
#define KSTRE 136   // Ks row stride (bf16 elems), 272B: 16B-aligned rows
#define VSTRM 40    // Vt row stride (m dim),       80B:  16B-aligned rows
#define PSTR  40    // Ps row stride
__global__ __launch_bounds__(256) void retention_mfma(
    const float* __restrict__ Q, const float* __restrict__ K,
    const float* __restrict__ V, float* __restrict__ Y)
{
    __shared__ short Ks[32 * KSTRE];      // 8704 B
    __shared__ short Vt[128 * VSTRM];     // 10240 B
    __shared__ short Ps[4][16 * PSTR];    // 5120 B
    int tid = threadIdx.x;
    int w    = tid >> 6;
    int lane = tid & 63;
    int q    = lane >> 4;     // quad 0..3
    int lr   = lane & 15;
    int h = blockIdx.y;
    int b = blockIdx.z;
    size_t bL = (size_t)b * LL;
    int hoff = h * HD;

    // decay constants
    const float lg_lo = -3.4657359027997265f;   // log(1/32)
    const float lg_hi = -6.2383246250395075f;   // log(1/512)
    float gamma = 1.f - expf(lg_lo + (lg_hi - lg_lo) * ((float)h / 7.f));
    float logg = logf(gamma);
    float gm32 = expf(-32.f * logg);            // gamma^-32 (tile-step factor)
    float rf[4];
    #pragma unroll
    for (int r = 0; r < 4; ++r) rf[r] = expf(logg * (float)(q * 4 + r));
    float cf0 = expf(-logg * (float)lr);
    float cf1 = expf(-logg * (float)(16 + lr));
    int dqlr = q * 4 - lr;     // d = dt + dqlr + r  (nh=0); -16 for nh=1

    int sr = tid >> 3;          // staging row 0..31
    int sc0 = (tid & 7) * 16;   // staging col base

    #pragma unroll 1
    for (int pass = 0; pass < 2; ++pass) {
        int jt = (pass == 0) ? blockIdx.x : (31 - blockIdx.x);
        int l0 = jt * 64;
        int l0w = l0 + w * 16;
        int ntiles = 2 * jt + 2;

        // Q fragments (A-layout): row l0w+lr, e = q*8 + es*32 + j
        bf16x8 qf[4];
        {
            const float* qp = Q + (bL + l0w + lr) * DIM + hoff + q * 8;
            #pragma unroll
            for (int es = 0; es < 4; ++es) {
                float4 q0 = *(const float4*)(qp + es * 32);
                float4 q1 = *(const float4*)(qp + es * 32 + 4);
                bf16x8 f;
                f[0]=f2bf(q0.x); f[1]=f2bf(q0.y); f[2]=f2bf(q0.z); f[3]=f2bf(q0.w);
                f[4]=f2bf(q1.x); f[5]=f2bf(q1.y); f[6]=f2bf(q1.z); f[7]=f2bf(q1.w);
                qf[es] = f;
            }
        }
        f32x4 yacc[8];
        #pragma unroll
        for (int vt = 0; vt < 8; ++vt) yacc[vt] = (f32x4){0.f, 0.f, 0.f, 0.f};
        float tf = expf(logg * (float)l0w);     // gamma^(l0w - m0), m0=0

        // preload tile 0
        float4 kreg[4], vreg[4];
        {
            const float* kp = K + (bL + sr) * DIM + hoff + sc0;
            const float* vp = V + (bL + sr) * DIM + hoff + sc0;
            #pragma unroll
            for (int i = 0; i < 4; ++i) { kreg[i] = *(const float4*)(kp + 4*i); vreg[i] = *(const float4*)(vp + 4*i); }
        }

        #pragma unroll 1
        for (int mt = 0; mt < ntiles; ++mt) {
            int m0 = mt * 32;
            int dt = l0w - m0;
            __syncthreads();    // previous tile's LDS reads done
            // regs -> LDS
            {
                bf16x8 klo, khi;
                klo[0]=f2bf(kreg[0].x); klo[1]=f2bf(kreg[0].y); klo[2]=f2bf(kreg[0].z); klo[3]=f2bf(kreg[0].w);
                klo[4]=f2bf(kreg[1].x); klo[5]=f2bf(kreg[1].y); klo[6]=f2bf(kreg[1].z); klo[7]=f2bf(kreg[1].w);
                khi[0]=f2bf(kreg[2].x); khi[1]=f2bf(kreg[2].y); khi[2]=f2bf(kreg[2].z); khi[3]=f2bf(kreg[2].w);
                khi[4]=f2bf(kreg[3].x); khi[5]=f2bf(kreg[3].y); khi[6]=f2bf(kreg[3].z); khi[7]=f2bf(kreg[3].w);
                *(bf16x8*)&Ks[sr * KSTRE + sc0]     = klo;
                *(bf16x8*)&Ks[sr * KSTRE + sc0 + 8] = khi;
                #pragma unroll
                for (int i = 0; i < 4; ++i) {
                    Vt[(sc0 + 4*i + 0) * VSTRM + sr] = f2bf(vreg[i].x);
                    Vt[(sc0 + 4*i + 1) * VSTRM + sr] = f2bf(vreg[i].y);
                    Vt[(sc0 + 4*i + 2) * VSTRM + sr] = f2bf(vreg[i].z);
                    Vt[(sc0 + 4*i + 3) * VSTRM + sr] = f2bf(vreg[i].w);
                }
            }
            __syncthreads();
            // prefetch next tile while computing this one (vmcnt overlap)
            if (mt + 1 < ntiles) {
                const float* kp = K + (bL + (m0 + 32) + sr) * DIM + hoff + sc0;
                const float* vp = V + (bL + (m0 + 32) + sr) * DIM + hoff + sc0;
                #pragma unroll
                for (int i = 0; i < 4; ++i) { kreg[i] = *(const float4*)(kp + 4*i); vreg[i] = *(const float4*)(vp + 4*i); }
            }
            if (m0 <= l0w + 15) {   // not fully masked for this wave
                // S = Q K^T  (two 16x16 tiles over m)
                f32x4 sa0 = (f32x4){0.f,0.f,0.f,0.f};
                f32x4 sa1 = (f32x4){0.f,0.f,0.f,0.f};
                #pragma unroll
                for (int es = 0; es < 4; ++es) {
                    bf16x8 bk0 = *(const bf16x8*)&Ks[lr * KSTRE + q * 8 + es * 32];
                    bf16x8 bk1 = *(const bf16x8*)&Ks[(16 + lr) * KSTRE + q * 8 + es * 32];
                    sa0 = __builtin_amdgcn_mfma_f32_16x16x32_bf16(qf[es], bk0, sa0, 0, 0, 0);
                    sa1 = __builtin_amdgcn_mfma_f32_16x16x32_bf16(qf[es], bk1, sa1, 0, 0, 0);
                }
                // decay + mask, C-layout -> Ps (bf16)
                #pragma unroll
                for (int r = 0; r < 4; ++r) {
                    float p0 = sa0[r] * (rf[r] * cf0 * tf);
                    float p1 = sa1[r] * (rf[r] * cf1 * tf);
                    int d0 = dt + dqlr + r;
                    Ps[w][(q*4 + r) * PSTR + lr]      = (d0 >= 0)      ? f2bf(p0) : (short)0;
                    Ps[w][(q*4 + r) * PSTR + 16 + lr] = (d0 - 16 >= 0) ? f2bf(p1) : (short)0;
                }
                // read back in A-layout (within-wave RAW; DS ops in-order + waitcnt)
                bf16x8 pa = *(const bf16x8*)&Ps[w][lr * PSTR + q * 8];
                #pragma unroll
                for (int vt = 0; vt < 8; ++vt) {
                    bf16x8 bv = *(const bf16x8*)&Vt[(vt * 16 + lr) * VSTRM + q * 8];
                    yacc[vt] = __builtin_amdgcn_mfma_f32_16x16x32_bf16(pa, bv, yacc[vt], 0, 0, 0);
                }
            }
            tf *= gm32;
        }
        // epilogue: C-layout rows l0w + q*4 + r, cols vt*16 + lr
        float* yp = Y + (bL + l0w + q * 4) * DIM + hoff + lr;
        #pragma unroll
        for (int vt = 0; vt < 8; ++vt)
            #pragma unroll
            for (int r = 0; r < 4; ++r)
                yp[(size_t)r * DIM + vt * 16] = yacc[vt][r];
    }
}

// ---------------- groupnorm (per (n,h) over 128) * gate, in-place on Y ----------------
__global__ __launch_bounds__(256) void gn_gate_kernel(
    float* __restrict__ Y, const float* __restrict__ G,
    const float* __restrict__ w, const float* __restrict__ b)
{
    int tid = threadIdx.x;
    int wid = tid >> 6, lane = tid & 63;
    int grp = blockIdx.x * 4 + wid;     // [0, N*H)
    int n = grp >> 3, h = grp & 7;
    size_t base = (size_t)n * DIM + h * HD + lane * 2;
    float2 y = *(float2*)(Y + base);
    float s = y.x + y.y, ss = y.x * y.x + y.y * y.y;
    #pragma unroll
    for (int o = 32; o > 0; o >>= 1) { s += __shfl_down(s, o); ss += __shfl_down(ss, o); }
    s = __shfl(s, 0); ss = __shfl(ss, 0);
    float mu  = s * (1.f / HD);
    float var = ss * (1.f / HD) - mu * mu;
    float rs  = rsqrtf(var + 1e-5f);
    float2 wv = *(const float2*)(w + h * HD + lane * 2);
    float2 bv = *(const float2*)(b + h * HD + lane * 2);
    float2 gv = *(const float2*)(G + base);
    float g0 = gv.x / (1.f + expf(-gv.x));   // g*sigmoid(g)
    float g1 = gv.y / (1.f + expf(-gv.y));
    float2 o;
    o.x = ((y.x - mu) * rs * wv.x + bv.x) * g0;
    o.y = ((y.y - mu) * rs * wv.y + bv.y) * g1;
    *(float2*)(Y + base) = o;
}

extern "C" void kernel_launch(void* const* d_in, const int* in_sizes, int n_in,
                              void* d_out, int out_size, void* d_ws, size_t ws_size,
                              hipStream_t stream)
{
    const float* X0   = (const float*)d_in[0];
    const float* Wq   = (const float*)d_in[1];
    const float* Wk   = (const float*)d_in[2];
    const float* Wv   = (const float*)d_in[3];
    const float* WG   = (const float*)d_in[4];
    const float* WO   = (const float*)d_in[5];
    const float* gnw  = (const float*)d_in[6];
    const float* gnb  = (const float*)d_in[7];
    const float* ln1w = (const float*)d_in[8];
    const float* ln1b = (const float*)d_in[9];
    const float* ln2w = (const float*)d_in[10];
    const float* ln2b = (const float*)d_in[11];
    const float* fw1  = (const float*)d_in[12];
    const float* fb1  = (const float*)d_in[13];
    const float* fw2  = (const float*)d_in[14];
    const float* fb2  = (const float*)d_in[15];

    float* ws = (float*)d_ws;
    const size_t U = (size_t)NROWS * DIM;    // 4,194,304 floats = 16 MB
    float* sXn = ws + 0 * U;    // LN1 out, later Ylayer (attn+resid)
    float* sQ  = ws + 1 * U;    // Q, later LN2 out (h)
    float* sK  = ws + 2 * U;    // K, later FFN hidden (chunk) low half
    float* sV  = ws + 3 * U;    // V, later FFN hidden (chunk) high half
    float* sY  = ws + 4 * U;    // retention out -> gated (in-place)
    float* sG  = ws + 5 * U;    // gate input; first 12MB doubles as Wq/Wk/Wv transposed
    float* sX  = ws + 6 * U;    // X between layers
    float* sH1 = sK;            // 2048 x 4096 = 2 units
    float* sWt = sG;
    // total workspace: 7 * 16 MB = 112 MB

    for (int i = 0; i < 2; ++i) {
        const float* Xin = (i == 0) ? X0 : sX;
        float* Xout = (i == 1) ? (float*)d_out : sX;

        // LN1
        ln_kernel<<<NROWS, 256, 0, stream>>>(Xin, ln1w + i * DIM, ln1b + i * DIM, sXn);
        // transpose projection weights (h,d,e)->(d,h*e)
        dim3 tg(DIM, HEADS);
        transpose_w<<<tg, HD, 0, stream>>>(Wq + (size_t)i * HEADS * DIM * HD, sWt + 0 * 1048576);
        transpose_w<<<tg, HD, 0, stream>>>(Wk + (size_t)i * HEADS * DIM * HD, sWt + 1 * 1048576);
        transpose_w<<<tg, HD, 0, stream>>>(Wv + (size_t)i * HEADS * DIM * HD, sWt + 2 * 1048576);
        // projections (Wt must be read before gemm G overwrites sG)
        dim3 g1(DIM / BN, NROWS / BM);   // (16, 32)
        gemm_f32<0><<<g1, 256, 0, stream>>>(sXn, sWt + 0 * 1048576, sQ, nullptr, nullptr, NROWS, DIM, DIM);
        gemm_f32<0><<<g1, 256, 0, stream>>>(sXn, sWt + 1 * 1048576, sK, nullptr, nullptr, NROWS, DIM, DIM);
        gemm_f32<0><<<g1, 256, 0, stream>>>(sXn, sWt + 2 * 1048576, sV, nullptr, nullptr, NROWS, DIM, DIM);
        gemm_f32<0><<<g1, 256, 0, stream>>>(sXn, WG + (size_t)i * DIM * DIM, sG, nullptr, nullptr, NROWS, DIM, DIM);
        // xPos
        xpos_kernel<<<NROWS * 512 / 256, 256, 0, stream>>>(sQ, 0);
        xpos_kernel<<<NROWS * 512 / 256, 256, 0, stream>>>(sK, 1);
        // retention (bf16 MFMA, paired q-tiles for uniform load)
        dim3 rg(16, HEADS, BB);
        retention_mfma<<<rg, 256, 0, stream>>>(sQ, sK, sV, sY);
        // groupnorm + swish gate (in place on sY)
        gn_gate_kernel<<<NROWS * HEADS / 4, 256, 0, stream>>>(sY, sG, gnw + i * DIM, gnb + i * DIM);
        // W_O + residual -> Ylayer (sXn)
        gemm_f32<3><<<g1, 256, 0, stream>>>(sY, WO + (size_t)i * DIM * DIM, sXn, nullptr, Xin, NROWS, DIM, DIM);
        // LN2 -> sQ
        ln_kernel<<<NROWS, 256, 0, stream>>>(sXn, ln2w + i * DIM, ln2b + i * DIM, sQ);
        // FFN in 2 row-chunks of 2048 (hidden reuses freed K/V space)
        for (int rc = 0; rc < 2; ++rc) {
            const float* hA = sQ + (size_t)rc * 2048 * DIM;
            dim3 gf1(FFN_DIM / BN, 2048 / BM);   // (64, 16)
            gemm_f32<1><<<gf1, 256, 0, stream>>>(hA, fw1 + (size_t)i * DIM * FFN_DIM, sH1,
                                                 fb1 + i * FFN_DIM, nullptr, 2048, DIM, FFN_DIM);
            dim3 gf2(DIM / BN, 2048 / BM);       // (16, 16)
            gemm_f32<2><<<gf2, 256, 0, stream>>>(sH1, fw2 + (size_t)i * FFN_DIM * DIM,
                                                 Xout + (size_t)rc * 2048 * DIM,
                                                 fb2 + i * DIM, sXn + (size_t)rc * 2048 * DIM,
                                                 2048, FFN_DIM, DIM);
        }
    }
}

// Round 3
// 1097.999 us; speedup vs baseline: 7.1221x; 3.5924x over previous
//
#include <hip/hip_runtime.h>
#include <math.h>

#define DIM 1024
#define FFN_DIM 4096
#define HEADS 8
#define HD 128
#define BB 2
#define LL 2048
#define NROWS (BB*LL)   // 4096

typedef __attribute__((ext_vector_type(8))) short bf16x8;
typedef __attribute__((ext_vector_type(4))) short bf16x4;
typedef __attribute__((ext_vector_type(2))) short bf16x2;
typedef __attribute__((ext_vector_type(4))) float f32x4;

__device__ inline short f2bf(float f) {
    unsigned u = __builtin_bit_cast(unsigned, f);
    unsigned r = (u + 0x7FFFu + ((u >> 16) & 1u)) >> 16;
    return (short)r;
}

__device__ __forceinline__ void gl_lds16(const void* g, void* l) {
    __builtin_amdgcn_global_load_lds(
        (const __attribute__((address_space(1))) unsigned int*)g,
        (__attribute__((address_space(3))) unsigned int*)l, 16, 0, 0);
}

// ---------------- LayerNorm (one block per row of 1024) -> bf16 out ----------------
__global__ __launch_bounds__(256) void ln_kernel_bf(
    const float* __restrict__ x, const float* __restrict__ w,
    const float* __restrict__ b, short* __restrict__ out)
{
    int row = blockIdx.x;
    int tid = threadIdx.x;
    const float* xr = x + (size_t)row * DIM;
    float4 v = *(const float4*)(xr + tid * 4);
    float s  = v.x + v.y + v.z + v.w;
    float ss = v.x*v.x + v.y*v.y + v.z*v.z + v.w*v.w;
    #pragma unroll
    for (int o = 32; o > 0; o >>= 1) { s += __shfl_down(s, o); ss += __shfl_down(ss, o); }
    __shared__ float red[10];
    int wid = tid >> 6;
    if ((tid & 63) == 0) { red[wid] = s; red[4 + wid] = ss; }
    __syncthreads();
    if (tid == 0) {
        float t  = red[0] + red[1] + red[2] + red[3];
        float t2 = red[4] + red[5] + red[6] + red[7];
        float mu  = t * (1.f / DIM);
        float var = t2 * (1.f / DIM) - mu * mu;
        red[8] = mu; red[9] = rsqrtf(var + 1e-5f);
    }
    __syncthreads();
    float mu = red[8], rs = red[9];
    float4 wv = *(const float4*)(w + tid * 4);
    float4 bv = *(const float4*)(b + tid * 4);
    bf16x4 o;
    o[0] = f2bf((v.x - mu) * rs * wv.x + bv.x);
    o[1] = f2bf((v.y - mu) * rs * wv.y + bv.y);
    o[2] = f2bf((v.z - mu) * rs * wv.z + bv.z);
    o[3] = f2bf((v.w - mu) * rs * wv.w + bv.w);
    *(bf16x4*)(out + (size_t)row * DIM + tid * 4) = o;
}

// ---------------- generic fp32(R,C) -> bf16 transpose (C,R), batched ----------------
__global__ __launch_bounds__(256) void transpose_cvt(
    const float* __restrict__ in, short* __restrict__ out,
    int R, int C, size_t ibs, size_t obs)
{
    __shared__ float t[32][33];
    int bz = blockIdx.z;
    int r0 = blockIdx.y * 32, c0 = blockIdx.x * 32;
    int tx = threadIdx.x & 31, ty = threadIdx.x >> 5;   // ty 0..7
    const float* ip = in + (size_t)bz * ibs;
    short* op = out + (size_t)bz * obs;
    #pragma unroll
    for (int i = 0; i < 4; ++i)
        t[ty + i * 8][tx] = ip[(size_t)(r0 + ty + i * 8) * C + c0 + tx];
    __syncthreads();
    #pragma unroll
    for (int i = 0; i < 4; ++i)
        op[(size_t)(c0 + ty + i * 8) * R + r0 + tx] = f2bf(t[tx][ty + i * 8]);
}

// ---------------- bf16 MFMA GEMM: C = A(N,K) @ Bt(M,K)^T  (m97 structure) ----------------
// EPI: 0 plain fp32 out, 1 bias+gelu -> bf16 out, 2 bias+residual fp32, 3 residual fp32
template<int EPI>
__global__ __launch_bounds__(256) void gemm_bf16(
    const short* __restrict__ A, const short* __restrict__ Bt,
    void* __restrict__ Cv, const float* __restrict__ bias,
    const float* __restrict__ R_, int N, int K, int M)
{
    __shared__ short As[128 * 32];   // 8 KB, row-major, 64B rows, XOR-swizzled segments
    __shared__ short Bs[128 * 32];
    int tid = threadIdx.x;
    int w = tid >> 6, lane = tid & 63;
    int q = lane >> 4, lr = lane & 15;
    int wr = w >> 1, wc = w & 1;
    int bm = blockIdx.y * 128, bn = blockIdx.x * 128;
    int srow = lane >> 2;     // 0..15 within a 16-row staging group
    int sseg = lane & 3;      // 16B segment slot in LDS

    f32x4 acc[4][4];
    #pragma unroll
    for (int mi = 0; mi < 4; ++mi)
        #pragma unroll
        for (int ni = 0; ni < 4; ++ni) acc[mi][ni] = (f32x4){0.f, 0.f, 0.f, 0.f};

    for (int k0 = 0; k0 < K; k0 += 32) {
        __syncthreads();    // prior iteration's LDS reads complete
        #pragma unroll
        for (int i = 0; i < 2; ++i) {
            int j = w * 2 + i;               // wave-uniform 16-row group
            int row = j * 16 + srow;
            int cseg = sseg ^ ((row >> 1) & 3);   // store swizzle
            gl_lds16(A  + (size_t)(bm + row) * K + k0 + cseg * 8, &As[j * 16 * 32]);
            gl_lds16(Bt + (size_t)(bn + row) * K + k0 + cseg * 8, &Bs[j * 16 * 32]);
        }
        __syncthreads();    // vmcnt(0) drain + barrier: LDS tiles ready
        bf16x8 af[4], bfr[4];
        #pragma unroll
        for (int mi = 0; mi < 4; ++mi) {
            int row = wr * 64 + mi * 16 + lr;
            af[mi] = *(const bf16x8*)&As[row * 32 + (q ^ ((row >> 1) & 3)) * 8];
        }
        #pragma unroll
        for (int ni = 0; ni < 4; ++ni) {
            int row = wc * 64 + ni * 16 + lr;
            bfr[ni] = *(const bf16x8*)&Bs[row * 32 + (q ^ ((row >> 1) & 3)) * 8];
        }
        #pragma unroll
        for (int mi = 0; mi < 4; ++mi)
            #pragma unroll
            for (int ni = 0; ni < 4; ++ni)
                acc[mi][ni] = __builtin_amdgcn_mfma_f32_16x16x32_bf16(af[mi], bfr[ni], acc[mi][ni], 0, 0, 0);
    }

    float* Cf = (float*)Cv;
    short* Cs = (short*)Cv;
    #pragma unroll
    for (int ni = 0; ni < 4; ++ni) {
        int col = bn + wc * 64 + ni * 16 + lr;
        float bi = 0.f;
        if constexpr (EPI == 1 || EPI == 2) bi = bias[col];
        #pragma unroll
        for (int mi = 0; mi < 4; ++mi) {
            int row0 = bm + wr * 64 + mi * 16 + q * 4;
            #pragma unroll
            for (int r = 0; r < 4; ++r) {
                size_t off = (size_t)(row0 + r) * M + col;
                float v = acc[mi][ni][r];
                if constexpr (EPI == 1) {
                    v += bi;
                    v = 0.5f * v * (1.f + erff(v * 0.70710678118654752f));
                    Cs[off] = f2bf(v);
                } else if constexpr (EPI == 2) {
                    Cf[off] = v + bi + R_[off];
                } else if constexpr (EPI == 3) {
                    Cf[off] = v + R_[off];
                } else {
                    Cf[off] = v;
                }
            }
        }
    }
}

// ---------------- xPos rotary, in-place on (N,1024) rows ----------------
__global__ __launch_bounds__(256) void xpos_kernel(float* __restrict__ X, int downscale)
{
    int idx = blockIdx.x * 256 + threadIdx.x;   // [0, NROWS*512)
    int n = idx >> 9;
    int c = idx & 511;          // pair index within row
    int j = c & 63;             // pair index within head
    int l = n & (LL - 1);       // sequence position
    float pos = (float)l;
    float bs = (2.f * (float)j + 0.4f * (float)HD) / (1.4f * (float)HD);
    float sc = powf(bs, pos * (1.f / 512.f));
    float s = downscale ? (1.f / sc) : sc;
    float invf = powf(10000.f, -(float)j * (1.f / 64.f));
    float ang = pos * invf;
    float sn, cn;
    sincosf(ang, &sn, &cn);
    float2 qv = *(float2*)(X + (size_t)n * DIM + c * 2);
    float cs = cn * s, ssn = sn * s;
    float2 o;
    o.x = qv.x * cs - qv.y * ssn;
    o.y = qv.y * cs + qv.x * ssn;
    *(float2*)(X + (size_t)n * DIM + c * 2) = o;
}

// ---------------- retention via bf16 MFMA, flash-style ----------------
#define KSTRE 136
#define VSTRM 40
#define PSTR  40
__global__ __launch_bounds__(256) void retention_mfma(
    const float* __restrict__ Q, const float* __restrict__ K,
    const float* __restrict__ V, float* __restrict__ Y)
{
    __shared__ short Ks[32 * KSTRE];
    __shared__ short Vt[128 * VSTRM];
    __shared__ short Ps[4][16 * PSTR];
    int tid = threadIdx.x;
    int w    = tid >> 6;
    int lane = tid & 63;
    int q    = lane >> 4;
    int lr   = lane & 15;
    int h = blockIdx.y;
    int b = blockIdx.z;
    size_t bL = (size_t)b * LL;
    int hoff = h * HD;

    const float lg_lo = -3.4657359027997265f;
    const float lg_hi = -6.2383246250395075f;
    float gamma = 1.f - expf(lg_lo + (lg_hi - lg_lo) * ((float)h / 7.f));
    float logg = logf(gamma);
    float gm32 = expf(-32.f * logg);
    float rf[4];
    #pragma unroll
    for (int r = 0; r < 4; ++r) rf[r] = expf(logg * (float)(q * 4 + r));
    float cf0 = expf(-logg * (float)lr);
    float cf1 = expf(-logg * (float)(16 + lr));
    int dqlr = q * 4 - lr;

    int sr = tid >> 3;
    int sc0 = (tid & 7) * 16;

    #pragma unroll 1
    for (int pass = 0; pass < 2; ++pass) {
        int jt = (pass == 0) ? blockIdx.x : (31 - blockIdx.x);
        int l0 = jt * 64;
        int l0w = l0 + w * 16;
        int ntiles = 2 * jt + 2;

        bf16x8 qf[4];
        {
            const float* qp = Q + (bL + l0w + lr) * DIM + hoff + q * 8;
            #pragma unroll
            for (int es = 0; es < 4; ++es) {
                float4 q0 = *(const float4*)(qp + es * 32);
                float4 q1 = *(const float4*)(qp + es * 32 + 4);
                bf16x8 f;
                f[0]=f2bf(q0.x); f[1]=f2bf(q0.y); f[2]=f2bf(q0.z); f[3]=f2bf(q0.w);
                f[4]=f2bf(q1.x); f[5]=f2bf(q1.y); f[6]=f2bf(q1.z); f[7]=f2bf(q1.w);
                qf[es] = f;
            }
        }
        f32x4 yacc[8];
        #pragma unroll
        for (int vt = 0; vt < 8; ++vt) yacc[vt] = (f32x4){0.f, 0.f, 0.f, 0.f};
        float tf = expf(logg * (float)l0w);

        float4 kreg[4], vreg[4];
        {
            const float* kp = K + (bL + sr) * DIM + hoff + sc0;
            const float* vp = V + (bL + sr) * DIM + hoff + sc0;
            #pragma unroll
            for (int i = 0; i < 4; ++i) { kreg[i] = *(const float4*)(kp + 4*i); vreg[i] = *(const float4*)(vp + 4*i); }
        }

        #pragma unroll 1
        for (int mt = 0; mt < ntiles; ++mt) {
            int m0 = mt * 32;
            int dt = l0w - m0;
            __syncthreads();
            {
                bf16x8 klo, khi;
                klo[0]=f2bf(kreg[0].x); klo[1]=f2bf(kreg[0].y); klo[2]=f2bf(kreg[0].z); klo[3]=f2bf(kreg[0].w);
                klo[4]=f2bf(kreg[1].x); klo[5]=f2bf(kreg[1].y); klo[6]=f2bf(kreg[1].z); klo[7]=f2bf(kreg[1].w);
                khi[0]=f2bf(kreg[2].x); khi[1]=f2bf(kreg[2].y); khi[2]=f2bf(kreg[2].z); khi[3]=f2bf(kreg[2].w);
                khi[4]=f2bf(kreg[3].x); khi[5]=f2bf(kreg[3].y); khi[6]=f2bf(kreg[3].z); khi[7]=f2bf(kreg[3].w);
                *(bf16x8*)&Ks[sr * KSTRE + sc0]     = klo;
                *(bf16x8*)&Ks[sr * KSTRE + sc0 + 8] = khi;
                #pragma unroll
                for (int i = 0; i < 4; ++i) {
                    Vt[(sc0 + 4*i + 0) * VSTRM + sr] = f2bf(vreg[i].x);
                    Vt[(sc0 + 4*i + 1) * VSTRM + sr] = f2bf(vreg[i].y);
                    Vt[(sc0 + 4*i + 2) * VSTRM + sr] = f2bf(vreg[i].z);
                    Vt[(sc0 + 4*i + 3) * VSTRM + sr] = f2bf(vreg[i].w);
                }
            }
            __syncthreads();
            if (mt + 1 < ntiles) {
                const float* kp = K + (bL + (m0 + 32) + sr) * DIM + hoff + sc0;
                const float* vp = V + (bL + (m0 + 32) + sr) * DIM + hoff + sc0;
                #pragma unroll
                for (int i = 0; i < 4; ++i) { kreg[i] = *(const float4*)(kp + 4*i); vreg[i] = *(const float4*)(vp + 4*i); }
            }
            if (m0 <= l0w + 15) {
                f32x4 sa0 = (f32x4){0.f,0.f,0.f,0.f};
                f32x4 sa1 = (f32x4){0.f,0.f,0.f,0.f};
                #pragma unroll
                for (int es = 0; es < 4; ++es) {
                    bf16x8 bk0 = *(const bf16x8*)&Ks[lr * KSTRE + q * 8 + es * 32];
                    bf16x8 bk1 = *(const bf16x8*)&Ks[(16 + lr) * KSTRE + q * 8 + es * 32];
                    sa0 = __builtin_amdgcn_mfma_f32_16x16x32_bf16(qf[es], bk0, sa0, 0, 0, 0);
                    sa1 = __builtin_amdgcn_mfma_f32_16x16x32_bf16(qf[es], bk1, sa1, 0, 0, 0);
                }
                #pragma unroll
                for (int r = 0; r < 4; ++r) {
                    float p0 = sa0[r] * (rf[r] * cf0 * tf);
                    float p1 = sa1[r] * (rf[r] * cf1 * tf);
                    int d0 = dt + dqlr + r;
                    Ps[w][(q*4 + r) * PSTR + lr]      = (d0 >= 0)      ? f2bf(p0) : (short)0;
                    Ps[w][(q*4 + r) * PSTR + 16 + lr] = (d0 - 16 >= 0) ? f2bf(p1) : (short)0;
                }
                bf16x8 pa = *(const bf16x8*)&Ps[w][lr * PSTR + q * 8];
                #pragma unroll
                for (int vt = 0; vt < 8; ++vt) {
                    bf16x8 bv = *(const bf16x8*)&Vt[(vt * 16 + lr) * VSTRM + q * 8];
                    yacc[vt] = __builtin_amdgcn_mfma_f32_16x16x32_bf16(pa, bv, yacc[vt], 0, 0, 0);
                }
            }
            tf *= gm32;
        }
        float* yp = Y + (bL + l0w + q * 4) * DIM + hoff + lr;
        #pragma unroll
        for (int vt = 0; vt < 8; ++vt)
            #pragma unroll
            for (int r = 0; r < 4; ++r)
                yp[(size_t)r * DIM + vt * 16] = yacc[vt][r];
    }
}

// ---------------- groupnorm * swish-gate -> bf16 out ----------------
__global__ __launch_bounds__(256) void gn_gate_kernel(
    const float* __restrict__ Y, const float* __restrict__ G,
    const float* __restrict__ w, const float* __restrict__ b,
    short* __restrict__ ybf)
{
    int tid = threadIdx.x;
    int wid = tid >> 6, lane = tid & 63;
    int grp = blockIdx.x * 4 + wid;
    int n = grp >> 3, h = grp & 7;
    size_t base = (size_t)n * DIM + h * HD + lane * 2;
    float2 y = *(const float2*)(Y + base);
    float s = y.x + y.y, ss = y.x * y.x + y.y * y.y;
    #pragma unroll
    for (int o = 32; o > 0; o >>= 1) { s += __shfl_down(s, o); ss += __shfl_down(ss, o); }
    s = __shfl(s, 0); ss = __shfl(ss, 0);
    float mu  = s * (1.f / HD);
    float var = ss * (1.f / HD) - mu * mu;
    float rs  = rsqrtf(var + 1e-5f);
    float2 wv = *(const float2*)(w + h * HD + lane * 2);
    float2 bv = *(const float2*)(b + h * HD + lane * 2);
    float2 gv = *(const float2*)(G + base);
    float g0 = gv.x / (1.f + expf(-gv.x));
    float g1 = gv.y / (1.f + expf(-gv.y));
    bf16x2 o;
    o[0] = f2bf(((y.x - mu) * rs * wv.x + bv.x) * g0);
    o[1] = f2bf(((y.y - mu) * rs * wv.y + bv.y) * g1);
    *(bf16x2*)(ybf + base) = o;
}

extern "C" void kernel_launch(void* const* d_in, const int* in_sizes, int n_in,
                              void* d_out, int out_size, void* d_ws, size_t ws_size,
                              hipStream_t stream)
{
    const float* X0   = (const float*)d_in[0];
    const float* Wq   = (const float*)d_in[1];
    const float* Wk   = (const float*)d_in[2];
    const float* Wv   = (const float*)d_in[3];
    const float* WG   = (const float*)d_in[4];
    const float* WO   = (const float*)d_in[5];
    const float* gnw  = (const float*)d_in[6];
    const float* gnb  = (const float*)d_in[7];
    const float* ln1w = (const float*)d_in[8];
    const float* ln1b = (const float*)d_in[9];
    const float* ln2w = (const float*)d_in[10];
    const float* ln2b = (const float*)d_in[11];
    const float* fw1  = (const float*)d_in[12];
    const float* fb1  = (const float*)d_in[13];
    const float* fw2  = (const float*)d_in[14];
    const float* fb2  = (const float*)d_in[15];

    float* ws = (float*)d_ws;
    const size_t U = (size_t)NROWS * DIM;    // 4M floats = 16 MB

    // fp32 buffers
    float* sQ  = ws + 1 * U;
    float* sK  = ws + 2 * U;
    float* sV  = ws + 3 * U;
    float* sG  = ws + 4 * U;
    float* sX  = ws + 5 * U;
    float* sXn = ws + 6 * U;    // Ylayer
    float* sY  = ws + 0 * U;    // retention out (overlays lnbf/weights after they're consumed)

    // bf16 overlays
    short* lnbf = (short*)(ws + 0 * U);              // 8 MB (LN1 out, later LN2 out)
    short* wqt  = lnbf + (size_t)NROWS * DIM;        // 2 MB each
    short* wkt  = wqt + (size_t)DIM * DIM;
    short* wvt  = wkt + (size_t)DIM * DIM;
    short* wgt  = wvt + (size_t)DIM * DIM;           // U0 ends exactly here
    short* ybf  = (short*)(ws + 1 * U);              // 8 MB (after retention: sQ dead)
    short* wot  = ybf + (size_t)NROWS * DIM;         // 2 MB
    short* h1   = (short*)(ws + 2 * U);              // 32 MB = U2+U3 (after retention: sK,sV dead)
    short* fw1t = (short*)(ws + 4 * U);              // 8 MB (after gn_gate: sG dead)
    short* fw2t = fw1t + (size_t)DIM * FFN_DIM;      // 8 MB

    for (int i = 0; i < 2; ++i) {
        const float* Xin = (i == 0) ? X0 : sX;
        float* Xout = (i == 1) ? (float*)d_out : sX;

        // LN1 -> bf16
        ln_kernel_bf<<<NROWS, 256, 0, stream>>>(Xin, ln1w + i * DIM, ln1b + i * DIM, lnbf);
        // weight transposes: (h,d,e)->(he,d) ; (d,v)->(v,d)
        dim3 tq(HD / 32, DIM / 32, HEADS);
        transpose_cvt<<<tq, 256, 0, stream>>>(Wq + (size_t)i * HEADS * DIM * HD, wqt, DIM, HD, (size_t)DIM * HD, (size_t)HD * DIM);
        transpose_cvt<<<tq, 256, 0, stream>>>(Wk + (size_t)i * HEADS * DIM * HD, wkt, DIM, HD, (size_t)DIM * HD, (size_t)HD * DIM);
        transpose_cvt<<<tq, 256, 0, stream>>>(Wv + (size_t)i * HEADS * DIM * HD, wvt, DIM, HD, (size_t)DIM * HD, (size_t)HD * DIM);
        dim3 tg(DIM / 32, DIM / 32, 1);
        transpose_cvt<<<tg, 256, 0, stream>>>(WG + (size_t)i * DIM * DIM, wgt, DIM, DIM, 0, 0);
        // projections: (4096,1024)x(1024,1024)
        dim3 gp(DIM / 128, NROWS / 128);   // (8,32)
        gemm_bf16<0><<<gp, 256, 0, stream>>>(lnbf, wqt, sQ, nullptr, nullptr, NROWS, DIM, DIM);
        gemm_bf16<0><<<gp, 256, 0, stream>>>(lnbf, wkt, sK, nullptr, nullptr, NROWS, DIM, DIM);
        gemm_bf16<0><<<gp, 256, 0, stream>>>(lnbf, wvt, sV, nullptr, nullptr, NROWS, DIM, DIM);
        gemm_bf16<0><<<gp, 256, 0, stream>>>(lnbf, wgt, sG, nullptr, nullptr, NROWS, DIM, DIM);
        // xPos
        xpos_kernel<<<NROWS * 512 / 256, 256, 0, stream>>>(sQ, 0);
        xpos_kernel<<<NROWS * 512 / 256, 256, 0, stream>>>(sK, 1);
        // retention -> sY (overwrites U0: lnbf/wqkvt dead)
        dim3 rg(16, HEADS, BB);
        retention_mfma<<<rg, 256, 0, stream>>>(sQ, sK, sV, sY);
        // groupnorm + gate -> ybf (U1: sQ dead)
        gn_gate_kernel<<<NROWS * HEADS / 4, 256, 0, stream>>>(sY, sG, gnw + i * DIM, gnb + i * DIM, ybf);
        // W_O transpose (v,d)->(d,v) and gemm + residual -> sXn
        transpose_cvt<<<tg, 256, 0, stream>>>(WO + (size_t)i * DIM * DIM, wot, DIM, DIM, 0, 0);
        gemm_bf16<3><<<gp, 256, 0, stream>>>(ybf, wot, sXn, nullptr, Xin, NROWS, DIM, DIM);
        // LN2 -> lnbf (U0: sY dead after gn_gate)
        ln_kernel_bf<<<NROWS, 256, 0, stream>>>(sXn, ln2w + i * DIM, ln2b + i * DIM, lnbf);
        // FFN weight transposes (sG dead)
        dim3 t1(FFN_DIM / 32, DIM / 32, 1);
        transpose_cvt<<<t1, 256, 0, stream>>>(fw1 + (size_t)i * DIM * FFN_DIM, fw1t, DIM, FFN_DIM, 0, 0);
        dim3 t2(DIM / 32, FFN_DIM / 32, 1);
        transpose_cvt<<<t2, 256, 0, stream>>>(fw2 + (size_t)i * FFN_DIM * DIM, fw2t, FFN_DIM, DIM, 0, 0);
        // FFN1: (4096,1024)x(1024,4096) + bias + gelu -> h1 bf16 (U2+U3)
        dim3 gf1(FFN_DIM / 128, NROWS / 128);   // (32,32)
        gemm_bf16<1><<<gf1, 256, 0, stream>>>(lnbf, fw1t, h1, fb1 + i * FFN_DIM, nullptr, NROWS, DIM, FFN_DIM);
        // FFN2: (4096,4096)x(4096,1024) + bias + residual -> Xout fp32
        dim3 gf2(DIM / 128, NROWS / 128);       // (8,32)
        gemm_bf16<2><<<gf2, 256, 0, stream>>>(h1, fw2t, Xout, fb2 + i * DIM, sXn, NROWS, FFN_DIM, DIM);
    }
}

// Round 4
// 944.701 us; speedup vs baseline: 8.2778x; 1.1623x over previous
//
#include <hip/hip_runtime.h>
#include <math.h>

#define DIM 1024
#define FFN_DIM 4096
#define HEADS 8
#define HD 128
#define BB 2
#define LL 2048
#define NROWS (BB*LL)   // 4096

typedef __attribute__((ext_vector_type(8))) short bf16x8;
typedef __attribute__((ext_vector_type(4))) short bf16x4;
typedef __attribute__((ext_vector_type(2))) short bf16x2;
typedef __attribute__((ext_vector_type(4))) float f32x4;

__device__ inline short f2bf(float f) {
    unsigned u = __builtin_bit_cast(unsigned, f);
    unsigned r = (u + 0x7FFFu + ((u >> 16) & 1u)) >> 16;
    return (short)r;
}

__device__ __forceinline__ void gl_lds16(const void* g, void* l) {
    __builtin_amdgcn_global_load_lds(
        (const __attribute__((address_space(1))) unsigned int*)g,
        (__attribute__((address_space(3))) unsigned int*)l, 16, 0, 0);
}

// ---------------- LayerNorm (one block per row of 1024) -> bf16 out ----------------
__global__ __launch_bounds__(256) void ln_kernel_bf(
    const float* __restrict__ x, const float* __restrict__ w,
    const float* __restrict__ b, short* __restrict__ out)
{
    int row = blockIdx.x;
    int tid = threadIdx.x;
    const float* xr = x + (size_t)row * DIM;
    float4 v = *(const float4*)(xr + tid * 4);
    float s  = v.x + v.y + v.z + v.w;
    float ss = v.x*v.x + v.y*v.y + v.z*v.z + v.w*v.w;
    #pragma unroll
    for (int o = 32; o > 0; o >>= 1) { s += __shfl_down(s, o); ss += __shfl_down(ss, o); }
    __shared__ float red[10];
    int wid = tid >> 6;
    if ((tid & 63) == 0) { red[wid] = s; red[4 + wid] = ss; }
    __syncthreads();
    if (tid == 0) {
        float t  = red[0] + red[1] + red[2] + red[3];
        float t2 = red[4] + red[5] + red[6] + red[7];
        float mu  = t * (1.f / DIM);
        float var = t2 * (1.f / DIM) - mu * mu;
        red[8] = mu; red[9] = rsqrtf(var + 1e-5f);
    }
    __syncthreads();
    float mu = red[8], rs = red[9];
    float4 wv = *(const float4*)(w + tid * 4);
    float4 bv = *(const float4*)(b + tid * 4);
    bf16x4 o;
    o[0] = f2bf((v.x - mu) * rs * wv.x + bv.x);
    o[1] = f2bf((v.y - mu) * rs * wv.y + bv.y);
    o[2] = f2bf((v.z - mu) * rs * wv.z + bv.z);
    o[3] = f2bf((v.w - mu) * rs * wv.w + bv.w);
    *(bf16x4*)(out + (size_t)row * DIM + tid * 4) = o;
}

// ---------------- generic fp32(R,C) -> bf16 transpose (C,R), batched ----------------
__global__ __launch_bounds__(256) void transpose_cvt(
    const float* __restrict__ in, short* __restrict__ out,
    int R, int C, size_t ibs, size_t obs)
{
    __shared__ float t[32][33];
    int bz = blockIdx.z;
    int r0 = blockIdx.y * 32, c0 = blockIdx.x * 32;
    int tx = threadIdx.x & 31, ty = threadIdx.x >> 5;   // ty 0..7
    const float* ip = in + (size_t)bz * ibs;
    short* op = out + (size_t)bz * obs;
    #pragma unroll
    for (int i = 0; i < 4; ++i)
        t[ty + i * 8][tx] = ip[(size_t)(r0 + ty + i * 8) * C + c0 + tx];
    __syncthreads();
    #pragma unroll
    for (int i = 0; i < 4; ++i)
        op[(size_t)(c0 + ty + i * 8) * R + r0 + tx] = f2bf(t[tx][ty + i * 8]);
}

// ---------------- V (NROWS,DIM) fp32 -> Vt bf16 [bh][v][l] ----------------
__global__ __launch_bounds__(256) void vt_cvt(
    const float* __restrict__ V, short* __restrict__ Vt)
{
    __shared__ float t[32][33];
    int r0 = blockIdx.y * 32, c0 = blockIdx.x * 32;   // r: global row (b*LL+l), c: h*HD+v
    int tx = threadIdx.x & 31, ty = threadIdx.x >> 5;
    #pragma unroll
    for (int i = 0; i < 4; ++i)
        t[ty + i * 8][tx] = V[(size_t)(r0 + ty + i * 8) * DIM + c0 + tx];
    __syncthreads();
    int b = r0 >> 11;
    int l = (r0 & (LL - 1));
    #pragma unroll
    for (int i = 0; i < 4; ++i) {
        int c = c0 + ty + i * 8;
        int h = c >> 7, v = c & 127;
        Vt[(((size_t)(b * HEADS + h) * HD + v) << 11) + l + tx] = f2bf(t[tx][ty + i * 8]);
    }
}

// ---------------- bf16 MFMA GEMM: C = A(N,K) @ Bt(M,K)^T  (m97 structure) ----------------
// EPI: 0 plain fp32, 1 bias+gelu->bf16, 2 bias+residual fp32, 3 residual fp32,
//      4 QKVG 4-way split fp32 (col>>10 selects Cv/Cx1/Cx2/Cx3, each (N,1024))
template<int EPI>
__global__ __launch_bounds__(256) void gemm_bf16(
    const short* __restrict__ A, const short* __restrict__ Bt,
    void* __restrict__ Cv, const float* __restrict__ bias,
    const float* __restrict__ R_,
    float* __restrict__ Cx1, float* __restrict__ Cx2, float* __restrict__ Cx3,
    int N, int K, int M)
{
    __shared__ short As[128 * 32];
    __shared__ short Bs[128 * 32];
    int tid = threadIdx.x;
    int w = tid >> 6, lane = tid & 63;
    int q = lane >> 4, lr = lane & 15;
    int wr = w >> 1, wc = w & 1;
    int bm = blockIdx.y * 128, bn = blockIdx.x * 128;
    int srow = lane >> 2;
    int sseg = lane & 3;

    f32x4 acc[4][4];
    #pragma unroll
    for (int mi = 0; mi < 4; ++mi)
        #pragma unroll
        for (int ni = 0; ni < 4; ++ni) acc[mi][ni] = (f32x4){0.f, 0.f, 0.f, 0.f};

    for (int k0 = 0; k0 < K; k0 += 32) {
        __syncthreads();
        #pragma unroll
        for (int i = 0; i < 2; ++i) {
            int j = w * 2 + i;
            int row = j * 16 + srow;
            int cseg = sseg ^ ((row >> 1) & 3);
            gl_lds16(A  + (size_t)(bm + row) * K + k0 + cseg * 8, &As[j * 16 * 32]);
            gl_lds16(Bt + (size_t)(bn + row) * K + k0 + cseg * 8, &Bs[j * 16 * 32]);
        }
        __syncthreads();
        bf16x8 af[4], bfr[4];
        #pragma unroll
        for (int mi = 0; mi < 4; ++mi) {
            int row = wr * 64 + mi * 16 + lr;
            af[mi] = *(const bf16x8*)&As[row * 32 + (q ^ ((row >> 1) & 3)) * 8];
        }
        #pragma unroll
        for (int ni = 0; ni < 4; ++ni) {
            int row = wc * 64 + ni * 16 + lr;
            bfr[ni] = *(const bf16x8*)&Bs[row * 32 + (q ^ ((row >> 1) & 3)) * 8];
        }
        #pragma unroll
        for (int mi = 0; mi < 4; ++mi)
            #pragma unroll
            for (int ni = 0; ni < 4; ++ni)
                acc[mi][ni] = __builtin_amdgcn_mfma_f32_16x16x32_bf16(af[mi], bfr[ni], acc[mi][ni], 0, 0, 0);
    }

    float* Cf = (float*)Cv;
    short* Cs = (short*)Cv;
    #pragma unroll
    for (int ni = 0; ni < 4; ++ni) {
        int col = bn + wc * 64 + ni * 16 + lr;
        float bi = 0.f;
        if constexpr (EPI == 1 || EPI == 2) bi = bias[col];
        #pragma unroll
        for (int mi = 0; mi < 4; ++mi) {
            int row0 = bm + wr * 64 + mi * 16 + q * 4;
            #pragma unroll
            for (int r = 0; r < 4; ++r) {
                size_t off = (size_t)(row0 + r) * M + col;
                float v = acc[mi][ni][r];
                if constexpr (EPI == 1) {
                    v += bi;
                    v = 0.5f * v * (1.f + erff(v * 0.70710678118654752f));
                    Cs[off] = f2bf(v);
                } else if constexpr (EPI == 2) {
                    Cf[off] = v + bi + R_[off];
                } else if constexpr (EPI == 3) {
                    Cf[off] = v + R_[off];
                } else if constexpr (EPI == 4) {
                    int sel = col >> 10;   // block-uniform (bn is a multiple of 128)
                    float* o = (sel == 0) ? Cf : (sel == 1) ? Cx1 : (sel == 2) ? Cx2 : Cx3;
                    o[(size_t)(row0 + r) * DIM + (col & (DIM - 1))] = v;
                } else {
                    Cf[off] = v;
                }
            }
        }
    }
}

// ---------------- xPos rotary: fp32 in -> bf16 out ----------------
__global__ __launch_bounds__(256) void xpos_cvt(
    const float* __restrict__ X, short* __restrict__ Ob, int downscale)
{
    int idx = blockIdx.x * 256 + threadIdx.x;   // [0, NROWS*512)
    int n = idx >> 9;
    int c = idx & 511;          // pair index within row
    int j = c & 63;             // pair index within head
    int l = n & (LL - 1);       // sequence position
    float pos = (float)l;
    float bs = (2.f * (float)j + 0.4f * (float)HD) / (1.4f * (float)HD);
    float sc = powf(bs, pos * (1.f / 512.f));
    float s = downscale ? (1.f / sc) : sc;
    float invf = powf(10000.f, -(float)j * (1.f / 64.f));
    float ang = pos * invf;
    float sn, cn;
    sincosf(ang, &sn, &cn);
    float2 qv = *(const float2*)(X + (size_t)n * DIM + c * 2);
    float cs = cn * s, ssn = sn * s;
    bf16x2 o;
    o[0] = f2bf(qv.x * cs - qv.y * ssn);
    o[1] = f2bf(qv.y * cs + qv.x * ssn);
    *(bf16x2*)(Ob + (size_t)n * DIM + c * 2) = o;
}

// ---------------- retention v2: bf16 inputs, global_load_lds staging, dbuf ----------------
// grid (bh=16, pair=16): linear id % 8 == h -> same-(b,h) blocks share an XCD L2.
// Block: 4 waves, one 64-row q-tile per pass; passes jt=pair and 31-pair (66 m-tiles).
#define PSTR 40
__global__ __launch_bounds__(256) void retention_mfma2(
    const short* __restrict__ Qb, const short* __restrict__ Kb,
    const short* __restrict__ Vt, float* __restrict__ Y)
{
    __shared__ __align__(16) short Ks[2][32 * 128];   // 8 KB per buf
    __shared__ __align__(16) short Vs[2][128 * 32];   // 8 KB per buf
    __shared__ __align__(16) short Ps[4][16 * PSTR];
    int tid = threadIdx.x;
    int w = tid >> 6, lane = tid & 63;
    int q = lane >> 4, lr = lane & 15;
    int bh = blockIdx.x;
    int b = bh >> 3, h = bh & 7;
    size_t bL = (size_t)b * LL;
    const short* Kbh = Kb + (bL << 10) + (h << 7);
    const short* Qbh = Qb + (bL << 10) + (h << 7);
    const short* Vbh = Vt + ((size_t)bh << 18);    // bh * 128 * 2048
    float* Ybh = Y + (bL << 10) + (h << 7);

    const float lg_lo = -3.4657359027997265f;   // log(1/32)
    const float lg_hi = -6.2383246250395075f;   // log(1/512)
    float gamma = 1.f - expf(lg_lo + (lg_hi - lg_lo) * ((float)h / 7.f));
    float logg = logf(gamma);
    float gm32 = expf(-32.f * logg);
    float rf[4];
    #pragma unroll
    for (int r = 0; r < 4; ++r) rf[r] = expf(logg * (float)(q * 4 + r));
    float cf0 = expf(-logg * (float)lr);
    float cf1 = expf(-logg * (float)(16 + lr));
    int dqlr = q * 4 - lr;

    // staging lane roles
    int krow = lane >> 4;     // 0..3
    int kslot = lane & 15;
    int vrow = lane >> 2;     // 0..15
    int vslot = lane & 3;

    #pragma unroll 1
    for (int pass = 0; pass < 2; ++pass) {
        int jt = pass ? (31 - blockIdx.y) : blockIdx.y;
        int l0w = jt * 64 + w * 16;
        int ntiles = 2 * jt + 2;

        bf16x8 qf[4];
        {
            const short* qp = Qbh + ((size_t)(l0w + lr) << 10) + q * 8;
            #pragma unroll
            for (int es = 0; es < 4; ++es) qf[es] = *(const bf16x8*)(qp + es * 32);
        }
        f32x4 yacc[8];
        #pragma unroll
        for (int vt = 0; vt < 8; ++vt) yacc[vt] = (f32x4){0.f, 0.f, 0.f, 0.f};
        float tf = expf(logg * (float)l0w);

        // prologue: stage tile 0 -> buf 0
        #pragma unroll
        for (int i = 0; i < 2; ++i) {
            int kr = w * 8 + i * 4 + krow;
            gl_lds16(Kbh + ((size_t)kr << 10) + ((kslot ^ (kr & 15)) << 3),
                     &Ks[0][(w * 8 + i * 4) * 128]);
            int vr = w * 32 + i * 16 + vrow;
            gl_lds16(Vbh + ((size_t)vr << 11) + ((vslot ^ (vr & 3)) << 3),
                     &Vs[0][(w * 32 + i * 16) * 32]);
        }

        #pragma unroll 1
        for (int mt = 0; mt < ntiles; ++mt) {
            int cur = mt & 1;
            int m0 = mt * 32;
            __syncthreads();    // drains staged loads for buf[cur]; protects buf reuse
            if (mt + 1 < ntiles) {
                int m1 = m0 + 32;
                #pragma unroll
                for (int i = 0; i < 2; ++i) {
                    int kr = w * 8 + i * 4 + krow;
                    gl_lds16(Kbh + ((size_t)(m1 + kr) << 10) + ((kslot ^ (kr & 15)) << 3),
                             &Ks[cur ^ 1][(w * 8 + i * 4) * 128]);
                    int vr = w * 32 + i * 16 + vrow;
                    gl_lds16(Vbh + ((size_t)vr << 11) + m1 + ((vslot ^ (vr & 3)) << 3),
                             &Vs[cur ^ 1][(w * 32 + i * 16) * 32]);
                }
            }
            if (m0 <= l0w + 15) {
                int dt = l0w - m0;
                f32x4 sa0 = (f32x4){0.f,0.f,0.f,0.f};
                f32x4 sa1 = (f32x4){0.f,0.f,0.f,0.f};
                #pragma unroll
                for (int es = 0; es < 4; ++es) {
                    int slot = ((es * 4 + q) ^ lr) * 8;
                    bf16x8 bk0 = *(const bf16x8*)&Ks[cur][lr * 128 + slot];
                    bf16x8 bk1 = *(const bf16x8*)&Ks[cur][(16 + lr) * 128 + slot];
                    sa0 = __builtin_amdgcn_mfma_f32_16x16x32_bf16(qf[es], bk0, sa0, 0, 0, 0);
                    sa1 = __builtin_amdgcn_mfma_f32_16x16x32_bf16(qf[es], bk1, sa1, 0, 0, 0);
                }
                #pragma unroll
                for (int r = 0; r < 4; ++r) {
                    float p0 = sa0[r] * (rf[r] * cf0 * tf);
                    float p1 = sa1[r] * (rf[r] * cf1 * tf);
                    int d0 = dt + dqlr + r;
                    Ps[w][(q*4 + r) * PSTR + lr]      = (d0 >= 0)      ? f2bf(p0) : (short)0;
                    Ps[w][(q*4 + r) * PSTR + 16 + lr] = (d0 - 16 >= 0) ? f2bf(p1) : (short)0;
                }
                bf16x8 pa = *(const bf16x8*)&Ps[w][lr * PSTR + q * 8];
                int vslot_r = (q ^ (lr & 3)) * 8;
                #pragma unroll
                for (int vt = 0; vt < 8; ++vt) {
                    bf16x8 bv = *(const bf16x8*)&Vs[cur][(vt * 16 + lr) * 32 + vslot_r];
                    yacc[vt] = __builtin_amdgcn_mfma_f32_16x16x32_bf16(pa, bv, yacc[vt], 0, 0, 0);
                }
            }
            tf *= gm32;
        }
        __syncthreads();    // last tile's LDS reads done before next pass restages
        float* yp = Ybh + ((size_t)(l0w + q * 4) << 10) + lr;
        #pragma unroll
        for (int vt = 0; vt < 8; ++vt)
            #pragma unroll
            for (int r = 0; r < 4; ++r)
                yp[((size_t)r << 10) + vt * 16] = yacc[vt][r];
    }
}

// ---------------- groupnorm * swish-gate -> bf16 out ----------------
__global__ __launch_bounds__(256) void gn_gate_kernel(
    const float* __restrict__ Y, const float* __restrict__ G,
    const float* __restrict__ w, const float* __restrict__ b,
    short* __restrict__ ybf)
{
    int tid = threadIdx.x;
    int wid = tid >> 6, lane = tid & 63;
    int grp = blockIdx.x * 4 + wid;
    int n = grp >> 3, h = grp & 7;
    size_t base = (size_t)n * DIM + h * HD + lane * 2;
    float2 y = *(const float2*)(Y + base);
    float s = y.x + y.y, ss = y.x * y.x + y.y * y.y;
    #pragma unroll
    for (int o = 32; o > 0; o >>= 1) { s += __shfl_down(s, o); ss += __shfl_down(ss, o); }
    s = __shfl(s, 0); ss = __shfl(ss, 0);
    float mu  = s * (1.f / HD);
    float var = ss * (1.f / HD) - mu * mu;
    float rs  = rsqrtf(var + 1e-5f);
    float2 wv = *(const float2*)(w + h * HD + lane * 2);
    float2 bv = *(const float2*)(b + h * HD + lane * 2);
    float2 gv = *(const float2*)(G + base);
    float g0 = gv.x / (1.f + expf(-gv.x));
    float g1 = gv.y / (1.f + expf(-gv.y));
    bf16x2 o;
    o[0] = f2bf(((y.x - mu) * rs * wv.x + bv.x) * g0);
    o[1] = f2bf(((y.y - mu) * rs * wv.y + bv.y) * g1);
    *(bf16x2*)(ybf + base) = o;
}

extern "C" void kernel_launch(void* const* d_in, const int* in_sizes, int n_in,
                              void* d_out, int out_size, void* d_ws, size_t ws_size,
                              hipStream_t stream)
{
    const float* X0   = (const float*)d_in[0];
    const float* Wq   = (const float*)d_in[1];
    const float* Wk   = (const float*)d_in[2];
    const float* Wv   = (const float*)d_in[3];
    const float* WG   = (const float*)d_in[4];
    const float* WO   = (const float*)d_in[5];
    const float* gnw  = (const float*)d_in[6];
    const float* gnb  = (const float*)d_in[7];
    const float* ln1w = (const float*)d_in[8];
    const float* ln1b = (const float*)d_in[9];
    const float* ln2w = (const float*)d_in[10];
    const float* ln2b = (const float*)d_in[11];
    const float* fw1  = (const float*)d_in[12];
    const float* fb1  = (const float*)d_in[13];
    const float* fw2  = (const float*)d_in[14];
    const float* fb2  = (const float*)d_in[15];

    float* ws = (float*)d_ws;
    const size_t U = (size_t)NROWS * DIM;    // 4M floats = 16 MB

    // Arena (112 MB):
    // U0: lnbf(8MB) + wqkvgt(8MB, one contiguous 4096x1024 Bt)
    // U1: sQ fp32 -> Vt bf16 (8MB) -> fw1t(8)+fw2t(8)
    // U2: sK fp32 -> sY fp32 -> h1 low half
    // U3: sV fp32 -> ybf(8)+wot(2) -> h1 high half
    // U4: sG fp32 -> sXn
    // U5: Qb(8)+Kb(8) bf16
    // U6: sX (inter-layer X)
    short* lnbf  = (short*)(ws + 0 * U);
    short* wqkvg = lnbf + (size_t)NROWS * DIM;       // 4096x1024 bf16
    float* sQ  = ws + 1 * U;
    float* sK  = ws + 2 * U;
    float* sV  = ws + 3 * U;
    float* sG  = ws + 4 * U;
    short* Vt   = (short*)(ws + 1 * U);
    short* fw1t = (short*)(ws + 1 * U);
    short* fw2t = fw1t + (size_t)DIM * FFN_DIM;
    float* sY  = ws + 2 * U;
    short* h1   = (short*)(ws + 2 * U);              // 32 MB spanning U2+U3
    short* ybf  = (short*)(ws + 3 * U);
    short* wot  = ybf + (size_t)NROWS * DIM;
    float* sXn = ws + 4 * U;
    short* Qb   = (short*)(ws + 5 * U);
    short* Kb   = Qb + (size_t)NROWS * DIM;
    float* sX  = ws + 6 * U;

    for (int i = 0; i < 2; ++i) {
        const float* Xin = (i == 0) ? X0 : sX;
        float* Xout = (i == 1) ? (float*)d_out : sX;

        // LN1 -> bf16
        ln_kernel_bf<<<NROWS, 256, 0, stream>>>(Xin, ln1w + i * DIM, ln1b + i * DIM, lnbf);
        // weight transposes into one contiguous (4096,1024) Bt: [Wq|Wk|Wv|WG]
        dim3 tq(HD / 32, DIM / 32, HEADS);
        transpose_cvt<<<tq, 256, 0, stream>>>(Wq + (size_t)i * HEADS * DIM * HD, wqkvg + 0 * DIM * DIM, DIM, HD, (size_t)DIM * HD, (size_t)HD * DIM);
        transpose_cvt<<<tq, 256, 0, stream>>>(Wk + (size_t)i * HEADS * DIM * HD, wqkvg + 1 * DIM * DIM, DIM, HD, (size_t)DIM * HD, (size_t)HD * DIM);
        transpose_cvt<<<tq, 256, 0, stream>>>(Wv + (size_t)i * HEADS * DIM * HD, wqkvg + 2 * DIM * DIM, DIM, HD, (size_t)DIM * HD, (size_t)HD * DIM);
        dim3 tg(DIM / 32, DIM / 32, 1);
        transpose_cvt<<<tg, 256, 0, stream>>>(WG + (size_t)i * DIM * DIM, wqkvg + 3 * (size_t)DIM * DIM, DIM, DIM, 0, 0);
        // fused QKVG projection: (4096,1024) x (1024,4096), 4-way split epilogue
        dim3 gp4(4 * DIM / 128, NROWS / 128);   // (32,32)
        gemm_bf16<4><<<gp4, 256, 0, stream>>>(lnbf, wqkvg, sQ, nullptr, nullptr, sK, sV, sG, NROWS, DIM, 4 * DIM);
        // xPos -> bf16 Qb/Kb, then V -> Vt bf16 (overwrites sQ region after xpos)
        xpos_cvt<<<NROWS * 512 / 256, 256, 0, stream>>>(sQ, Qb, 0);
        xpos_cvt<<<NROWS * 512 / 256, 256, 0, stream>>>(sK, Kb, 1);
        dim3 vg(DIM / 32, NROWS / 32);
        vt_cvt<<<vg, 256, 0, stream>>>(sV, Vt);
        // retention -> sY (overwrites sK region; reads Qb/Kb/Vt)
        dim3 rg(16, 16);
        retention_mfma2<<<rg, 256, 0, stream>>>(Qb, Kb, Vt, sY);
        // groupnorm + gate -> ybf (overwrites sV region)
        gn_gate_kernel<<<NROWS * HEADS / 4, 256, 0, stream>>>(sY, sG, gnw + i * DIM, gnb + i * DIM, ybf);
        // W_O + residual -> sXn (overwrites sG region)
        transpose_cvt<<<tg, 256, 0, stream>>>(WO + (size_t)i * DIM * DIM, wot, DIM, DIM, 0, 0);
        dim3 gp(DIM / 128, NROWS / 128);   // (8,32)
        gemm_bf16<3><<<gp, 256, 0, stream>>>(ybf, wot, sXn, nullptr, Xin, nullptr, nullptr, nullptr, NROWS, DIM, DIM);
        // LN2 -> lnbf
        ln_kernel_bf<<<NROWS, 256, 0, stream>>>(sXn, ln2w + i * DIM, ln2b + i * DIM, lnbf);
        // FFN weight transposes (U1 free: Vt dead after retention)
        dim3 t1(FFN_DIM / 32, DIM / 32, 1);
        transpose_cvt<<<t1, 256, 0, stream>>>(fw1 + (size_t)i * DIM * FFN_DIM, fw1t, DIM, FFN_DIM, 0, 0);
        dim3 t2(DIM / 32, FFN_DIM / 32, 1);
        transpose_cvt<<<t2, 256, 0, stream>>>(fw2 + (size_t)i * FFN_DIM * DIM, fw2t, FFN_DIM, DIM, 0, 0);
        // FFN1: + bias + gelu -> h1 bf16 (U2+U3; ybf/wot dead)
        dim3 gf1(FFN_DIM / 128, NROWS / 128);   // (32,32)
        gemm_bf16<1><<<gf1, 256, 0, stream>>>(lnbf, fw1t, h1, fb1 + i * FFN_DIM, nullptr, nullptr, nullptr, nullptr, NROWS, DIM, FFN_DIM);
        // FFN2: + bias + residual -> Xout fp32
        dim3 gf2(DIM / 128, NROWS / 128);       // (8,32)
        gemm_bf16<2><<<gf2, 256, 0, stream>>>(h1, fw2t, Xout, fb2 + i * DIM, sXn, nullptr, nullptr, nullptr, NROWS, FFN_DIM, DIM);
    }
}

// Round 5
// 897.020 us; speedup vs baseline: 8.7178x; 1.0532x over previous
//
#include <hip/hip_runtime.h>
#include <math.h>

#define DIM 1024
#define FFN_DIM 4096
#define HEADS 8
#define HD 128
#define BB 2
#define LL 2048
#define NROWS (BB*LL)   // 4096

typedef __attribute__((ext_vector_type(8))) short bf16x8;
typedef __attribute__((ext_vector_type(4))) short bf16x4;
typedef __attribute__((ext_vector_type(2))) short bf16x2;
typedef __attribute__((ext_vector_type(4))) float f32x4;

__device__ inline short f2bf(float f) {
    unsigned u = __builtin_bit_cast(unsigned, f);
    unsigned r = (u + 0x7FFFu + ((u >> 16) & 1u)) >> 16;
    return (short)r;
}

__device__ __forceinline__ void gl_lds16(const void* g, void* l) {
    __builtin_amdgcn_global_load_lds(
        (const __attribute__((address_space(1))) unsigned int*)g,
        (__attribute__((address_space(3))) unsigned int*)l, 16, 0, 0);
}

// ---------------- LayerNorm (one block per row of 1024) -> bf16 out ----------------
__global__ __launch_bounds__(256) void ln_kernel_bf(
    const float* __restrict__ x, const float* __restrict__ w,
    const float* __restrict__ b, short* __restrict__ out)
{
    int row = blockIdx.x;
    int tid = threadIdx.x;
    const float* xr = x + (size_t)row * DIM;
    float4 v = *(const float4*)(xr + tid * 4);
    float s  = v.x + v.y + v.z + v.w;
    float ss = v.x*v.x + v.y*v.y + v.z*v.z + v.w*v.w;
    #pragma unroll
    for (int o = 32; o > 0; o >>= 1) { s += __shfl_down(s, o); ss += __shfl_down(ss, o); }
    __shared__ float red[10];
    int wid = tid >> 6;
    if ((tid & 63) == 0) { red[wid] = s; red[4 + wid] = ss; }
    __syncthreads();
    if (tid == 0) {
        float t  = red[0] + red[1] + red[2] + red[3];
        float t2 = red[4] + red[5] + red[6] + red[7];
        float mu  = t * (1.f / DIM);
        float var = t2 * (1.f / DIM) - mu * mu;
        red[8] = mu; red[9] = rsqrtf(var + 1e-5f);
    }
    __syncthreads();
    float mu = red[8], rs = red[9];
    float4 wv = *(const float4*)(w + tid * 4);
    float4 bv = *(const float4*)(b + tid * 4);
    bf16x4 o;
    o[0] = f2bf((v.x - mu) * rs * wv.x + bv.x);
    o[1] = f2bf((v.y - mu) * rs * wv.y + bv.y);
    o[2] = f2bf((v.z - mu) * rs * wv.z + bv.z);
    o[3] = f2bf((v.w - mu) * rs * wv.w + bv.w);
    *(bf16x4*)(out + (size_t)row * DIM + tid * 4) = o;
}

// ---------------- generic fp32(R,C) -> bf16 transpose (C,R), batched ----------------
__global__ __launch_bounds__(256) void transpose_cvt(
    const float* __restrict__ in, short* __restrict__ out,
    int R, int C, size_t ibs, size_t obs)
{
    __shared__ float t[32][33];
    int bz = blockIdx.z;
    int r0 = blockIdx.y * 32, c0 = blockIdx.x * 32;
    int tx = threadIdx.x & 31, ty = threadIdx.x >> 5;   // ty 0..7
    const float* ip = in + (size_t)bz * ibs;
    short* op = out + (size_t)bz * obs;
    #pragma unroll
    for (int i = 0; i < 4; ++i)
        t[ty + i * 8][tx] = ip[(size_t)(r0 + ty + i * 8) * C + c0 + tx];
    __syncthreads();
    #pragma unroll
    for (int i = 0; i < 4; ++i)
        op[(size_t)(c0 + ty + i * 8) * R + r0 + tx] = f2bf(t[tx][ty + i * 8]);
}

// ---------------- Vb bf16 (NROWS,DIM) -> Vt bf16 [bh][v][l] ----------------
__global__ __launch_bounds__(256) void vt_cvt(
    const short* __restrict__ Vb, short* __restrict__ Vt)
{
    __shared__ short t[32][34];
    int r0 = blockIdx.y * 32, c0 = blockIdx.x * 32;   // r: global row (b*LL+l), c: h*HD+v
    int tx = threadIdx.x & 31, ty = threadIdx.x >> 5;
    #pragma unroll
    for (int i = 0; i < 4; ++i)
        t[ty + i * 8][tx] = Vb[(size_t)(r0 + ty + i * 8) * DIM + c0 + tx];
    __syncthreads();
    int b = r0 >> 11;
    int l = (r0 & (LL - 1));
    #pragma unroll
    for (int i = 0; i < 4; ++i) {
        int c = c0 + ty + i * 8;
        int h = c >> 7, v = c & 127;
        Vt[(((size_t)(b * HEADS + h) * HD + v) << 11) + l + tx] = t[tx][ty + i * 8];
    }
}

// ---------------- bf16 MFMA GEMM: C = A(N,K) @ Bt(M,K)^T  (m97 + XCD swizzle) ----------------
// EPI: 0 plain fp32, 1 bias+gelu->bf16, 2 bias+residual fp32, 3 residual fp32,
//      4 QKVG: Q->rotary->bf16 P0, K->rotary(down)->bf16 P1, V->bf16 P2, G->fp32 P3
template<int EPI, int GX>
__global__ __launch_bounds__(256) void gemm_bf16(
    const short* __restrict__ A, const short* __restrict__ Bt,
    void* __restrict__ Cv, const float* __restrict__ bias,
    const float* __restrict__ R_,
    void* __restrict__ P1, void* __restrict__ P2, void* __restrict__ P3,
    int N, int K, int M)
{
    __shared__ short As[128 * 32];
    __shared__ short Bs[128 * 32];
    int tid = threadIdx.x;
    int w = tid >> 6, lane = tid & 63;
    int q = lane >> 4, lr = lane & 15;
    int wr = w >> 1, wc = w & 1;

    // XCD-aware tile remap: blocks with id%8==k form XCD k's compact region.
    int id = blockIdx.y * GX + blockIdx.x;
    int xcd = id & 7, j = id >> 3;
    constexpr int rx_n = GX / 8;                 // regions along x
    int tp = (GX * gridDim.y) >> 3;              // tiles per xcd
    int rh = tp >> 3;                            // region height (rw = 8)
    int lbx = j & 7, lby = j >> 3;
    int rx = xcd % rx_n, ry = xcd / rx_n;
    int bm = (ry * rh + lby) * 128;
    int bn = (rx * 8 + lbx) * 128;

    int srow = lane >> 2;
    int sseg = lane & 3;

    f32x4 acc[4][4];
    #pragma unroll
    for (int mi = 0; mi < 4; ++mi)
        #pragma unroll
        for (int ni = 0; ni < 4; ++ni) acc[mi][ni] = (f32x4){0.f, 0.f, 0.f, 0.f};

    for (int k0 = 0; k0 < K; k0 += 32) {
        __syncthreads();
        #pragma unroll
        for (int i = 0; i < 2; ++i) {
            int jj = w * 2 + i;
            int row = jj * 16 + srow;
            int cseg = sseg ^ ((row >> 1) & 3);
            gl_lds16(A  + (size_t)(bm + row) * K + k0 + cseg * 8, &As[jj * 16 * 32]);
            gl_lds16(Bt + (size_t)(bn + row) * K + k0 + cseg * 8, &Bs[jj * 16 * 32]);
        }
        __syncthreads();
        bf16x8 af[4], bfr[4];
        #pragma unroll
        for (int mi = 0; mi < 4; ++mi) {
            int row = wr * 64 + mi * 16 + lr;
            af[mi] = *(const bf16x8*)&As[row * 32 + (q ^ ((row >> 1) & 3)) * 8];
        }
        #pragma unroll
        for (int ni = 0; ni < 4; ++ni) {
            int row = wc * 64 + ni * 16 + lr;
            bfr[ni] = *(const bf16x8*)&Bs[row * 32 + (q ^ ((row >> 1) & 3)) * 8];
        }
        #pragma unroll
        for (int mi = 0; mi < 4; ++mi)
            #pragma unroll
            for (int ni = 0; ni < 4; ++ni)
                acc[mi][ni] = __builtin_amdgcn_mfma_f32_16x16x32_bf16(af[mi], bfr[ni], acc[mi][ni], 0, 0, 0);
    }

    if constexpr (EPI == 4) {
        // quarters of M=4096: 0=Q(rotary up), 1=K(rotary down), 2=V(bf16), 3=G(fp32)
        int sel = bn >> 10;                    // block-uniform
        int row_base = bm + wr * 64 + q * 4;   // +mi*16+r
        int l0 = row_base & (LL - 1);          // same b for whole block
        #pragma unroll
        for (int ni = 0; ni < 4; ++ni) {
            int col = bn + wc * 64 + ni * 16 + lr;
            int cq = col & (DIM - 1);
            if (sel <= 1) {
                int jj = (col & 127) >> 1;
                float lb = log2f((2.f * jj + 51.2f) / 179.2f);
                if (sel == 1) lb = -lb;        // downscale for K
                float invf = exp2f(-(float)jj * (13.287712379549449f / 64.f));
                float snb, cnb;
                sincosf((float)l0 * invf, &snb, &cnb);
                float scb = exp2f(lb * (float)l0 * (1.f / 512.f));
                float s1, c1, s16, c16;
                __sincosf(invf, &s1, &c1);
                __sincosf(16.f * invf, &s16, &c16);
                float st1 = exp2f(lb * (1.f / 512.f));
                float st16 = exp2f(lb * (16.f / 512.f));
                short* Ob = (short*)(sel == 0 ? Cv : P1);
                #pragma unroll
                for (int mi = 0; mi < 4; ++mi) {
                    float cr = cnb, sr = snb, sv = scb;
                    #pragma unroll
                    for (int r = 0; r < 4; ++r) {
                        float cs = cr * sv, ssn = sr * sv;
                        float v = acc[mi][ni][r];
                        float p = __shfl_xor(v, 1);
                        float o = (lr & 1) ? (v * cs + p * ssn) : (v * cs - p * ssn);
                        Ob[(size_t)(row_base + mi * 16 + r) * DIM + cq] = f2bf(o);
                        if (r < 3) {
                            float crn = cr * c1 - sr * s1;
                            sr = sr * c1 + cr * s1; cr = crn;
                            sv *= st1;
                        }
                    }
                    // advance base by 16 rows
                    float cbn = cnb * c16 - snb * s16;
                    snb = snb * c16 + cnb * s16; cnb = cbn;
                    scb *= st16;
                }
            } else if (sel == 2) {
                short* Vb = (short*)P2;
                #pragma unroll
                for (int mi = 0; mi < 4; ++mi)
                    #pragma unroll
                    for (int r = 0; r < 4; ++r)
                        Vb[(size_t)(row_base + mi * 16 + r) * DIM + cq] = f2bf(acc[mi][ni][r]);
            } else {
                float* Gf = (float*)P3;
                #pragma unroll
                for (int mi = 0; mi < 4; ++mi)
                    #pragma unroll
                    for (int r = 0; r < 4; ++r)
                        Gf[(size_t)(row_base + mi * 16 + r) * DIM + cq] = acc[mi][ni][r];
            }
        }
        return;
    }

    float* Cf = (float*)Cv;
    short* Cs = (short*)Cv;
    #pragma unroll
    for (int ni = 0; ni < 4; ++ni) {
        int col = bn + wc * 64 + ni * 16 + lr;
        float bi = 0.f;
        if constexpr (EPI == 1 || EPI == 2) bi = bias[col];
        #pragma unroll
        for (int mi = 0; mi < 4; ++mi) {
            int row0 = bm + wr * 64 + mi * 16 + q * 4;
            #pragma unroll
            for (int r = 0; r < 4; ++r) {
                size_t off = (size_t)(row0 + r) * M + col;
                float v = acc[mi][ni][r];
                if constexpr (EPI == 1) {
                    v += bi;
                    v = 0.5f * v * (1.f + erff(v * 0.70710678118654752f));
                    Cs[off] = f2bf(v);
                } else if constexpr (EPI == 2) {
                    Cf[off] = v + bi + R_[off];
                } else if constexpr (EPI == 3) {
                    Cf[off] = v + R_[off];
                } else {
                    Cf[off] = v;
                }
            }
        }
    }
}

// ---------------- retention: bf16 inputs, global_load_lds staging, dbuf ----------------
#define PSTR 40
__global__ __launch_bounds__(256) void retention_mfma2(
    const short* __restrict__ Qb, const short* __restrict__ Kb,
    const short* __restrict__ Vt, float* __restrict__ Y)
{
    __shared__ __align__(16) short Ks[2][32 * 128];
    __shared__ __align__(16) short Vs[2][128 * 32];
    __shared__ __align__(16) short Ps[4][16 * PSTR];
    int tid = threadIdx.x;
    int w = tid >> 6, lane = tid & 63;
    int q = lane >> 4, lr = lane & 15;
    int bh = blockIdx.x;
    int b = bh >> 3, h = bh & 7;
    size_t bL = (size_t)b * LL;
    const short* Kbh = Kb + (bL << 10) + (h << 7);
    const short* Qbh = Qb + (bL << 10) + (h << 7);
    const short* Vbh = Vt + ((size_t)bh << 18);
    float* Ybh = Y + (bL << 10) + (h << 7);

    const float lg_lo = -3.4657359027997265f;
    const float lg_hi = -6.2383246250395075f;
    float gamma = 1.f - expf(lg_lo + (lg_hi - lg_lo) * ((float)h / 7.f));
    float logg = logf(gamma);
    float gm32 = expf(-32.f * logg);
    float rf[4];
    #pragma unroll
    for (int r = 0; r < 4; ++r) rf[r] = expf(logg * (float)(q * 4 + r));
    float cf0 = expf(-logg * (float)lr);
    float cf1 = expf(-logg * (float)(16 + lr));
    int dqlr = q * 4 - lr;

    int krow = lane >> 4;
    int kslot = lane & 15;
    int vrow = lane >> 2;
    int vslot = lane & 3;

    #pragma unroll 1
    for (int pass = 0; pass < 2; ++pass) {
        int jt = pass ? (31 - blockIdx.y) : blockIdx.y;
        int l0w = jt * 64 + w * 16;
        int ntiles = 2 * jt + 2;

        bf16x8 qf[4];
        {
            const short* qp = Qbh + ((size_t)(l0w + lr) << 10) + q * 8;
            #pragma unroll
            for (int es = 0; es < 4; ++es) qf[es] = *(const bf16x8*)(qp + es * 32);
        }
        f32x4 yacc[8];
        #pragma unroll
        for (int vt = 0; vt < 8; ++vt) yacc[vt] = (f32x4){0.f, 0.f, 0.f, 0.f};
        float tf = expf(logg * (float)l0w);

        #pragma unroll
        for (int i = 0; i < 2; ++i) {
            int kr = w * 8 + i * 4 + krow;
            gl_lds16(Kbh + ((size_t)kr << 10) + ((kslot ^ (kr & 15)) << 3),
                     &Ks[0][(w * 8 + i * 4) * 128]);
            int vr = w * 32 + i * 16 + vrow;
            gl_lds16(Vbh + ((size_t)vr << 11) + ((vslot ^ (vr & 3)) << 3),
                     &Vs[0][(w * 32 + i * 16) * 32]);
        }

        #pragma unroll 1
        for (int mt = 0; mt < ntiles; ++mt) {
            int cur = mt & 1;
            int m0 = mt * 32;
            __syncthreads();
            if (mt + 1 < ntiles) {
                int m1 = m0 + 32;
                #pragma unroll
                for (int i = 0; i < 2; ++i) {
                    int kr = w * 8 + i * 4 + krow;
                    gl_lds16(Kbh + ((size_t)(m1 + kr) << 10) + ((kslot ^ (kr & 15)) << 3),
                             &Ks[cur ^ 1][(w * 8 + i * 4) * 128]);
                    int vr = w * 32 + i * 16 + vrow;
                    gl_lds16(Vbh + ((size_t)vr << 11) + m1 + ((vslot ^ (vr & 3)) << 3),
                             &Vs[cur ^ 1][(w * 32 + i * 16) * 32]);
                }
            }
            if (m0 <= l0w + 15) {
                int dt = l0w - m0;
                f32x4 sa0 = (f32x4){0.f,0.f,0.f,0.f};
                f32x4 sa1 = (f32x4){0.f,0.f,0.f,0.f};
                #pragma unroll
                for (int es = 0; es < 4; ++es) {
                    int slot = ((es * 4 + q) ^ lr) * 8;
                    bf16x8 bk0 = *(const bf16x8*)&Ks[cur][lr * 128 + slot];
                    bf16x8 bk1 = *(const bf16x8*)&Ks[cur][(16 + lr) * 128 + slot];
                    sa0 = __builtin_amdgcn_mfma_f32_16x16x32_bf16(qf[es], bk0, sa0, 0, 0, 0);
                    sa1 = __builtin_amdgcn_mfma_f32_16x16x32_bf16(qf[es], bk1, sa1, 0, 0, 0);
                }
                #pragma unroll
                for (int r = 0; r < 4; ++r) {
                    float p0 = sa0[r] * (rf[r] * cf0 * tf);
                    float p1 = sa1[r] * (rf[r] * cf1 * tf);
                    int d0 = dt + dqlr + r;
                    Ps[w][(q*4 + r) * PSTR + lr]      = (d0 >= 0)      ? f2bf(p0) : (short)0;
                    Ps[w][(q*4 + r) * PSTR + 16 + lr] = (d0 - 16 >= 0) ? f2bf(p1) : (short)0;
                }
                bf16x8 pa = *(const bf16x8*)&Ps[w][lr * PSTR + q * 8];
                int vslot_r = (q ^ (lr & 3)) * 8;
                #pragma unroll
                for (int vt = 0; vt < 8; ++vt) {
                    bf16x8 bv = *(const bf16x8*)&Vs[cur][(vt * 16 + lr) * 32 + vslot_r];
                    yacc[vt] = __builtin_amdgcn_mfma_f32_16x16x32_bf16(pa, bv, yacc[vt], 0, 0, 0);
                }
            }
            tf *= gm32;
        }
        __syncthreads();
        float* yp = Ybh + ((size_t)(l0w + q * 4) << 10) + lr;
        #pragma unroll
        for (int vt = 0; vt < 8; ++vt)
            #pragma unroll
            for (int r = 0; r < 4; ++r)
                yp[((size_t)r << 10) + vt * 16] = yacc[vt][r];
    }
}

// ---------------- groupnorm * swish-gate -> bf16 out ----------------
__global__ __launch_bounds__(256) void gn_gate_kernel(
    const float* __restrict__ Y, const float* __restrict__ G,
    const float* __restrict__ w, const float* __restrict__ b,
    short* __restrict__ ybf)
{
    int tid = threadIdx.x;
    int wid = tid >> 6, lane = tid & 63;
    int grp = blockIdx.x * 4 + wid;
    int n = grp >> 3, h = grp & 7;
    size_t base = (size_t)n * DIM + h * HD + lane * 2;
    float2 y = *(const float2*)(Y + base);
    float s = y.x + y.y, ss = y.x * y.x + y.y * y.y;
    #pragma unroll
    for (int o = 32; o > 0; o >>= 1) { s += __shfl_down(s, o); ss += __shfl_down(ss, o); }
    s = __shfl(s, 0); ss = __shfl(ss, 0);
    float mu  = s * (1.f / HD);
    float var = ss * (1.f / HD) - mu * mu;
    float rs  = rsqrtf(var + 1e-5f);
    float2 wv = *(const float2*)(w + h * HD + lane * 2);
    float2 bv = *(const float2*)(b + h * HD + lane * 2);
    float2 gv = *(const float2*)(G + base);
    float g0 = gv.x / (1.f + expf(-gv.x));
    float g1 = gv.y / (1.f + expf(-gv.y));
    bf16x2 o;
    o[0] = f2bf(((y.x - mu) * rs * wv.x + bv.x) * g0);
    o[1] = f2bf(((y.y - mu) * rs * wv.y + bv.y) * g1);
    *(bf16x2*)(ybf + base) = o;
}

extern "C" void kernel_launch(void* const* d_in, const int* in_sizes, int n_in,
                              void* d_out, int out_size, void* d_ws, size_t ws_size,
                              hipStream_t stream)
{
    const float* X0   = (const float*)d_in[0];
    const float* Wq   = (const float*)d_in[1];
    const float* Wk   = (const float*)d_in[2];
    const float* Wv   = (const float*)d_in[3];
    const float* WG   = (const float*)d_in[4];
    const float* WO   = (const float*)d_in[5];
    const float* gnw  = (const float*)d_in[6];
    const float* gnb  = (const float*)d_in[7];
    const float* ln1w = (const float*)d_in[8];
    const float* ln1b = (const float*)d_in[9];
    const float* ln2w = (const float*)d_in[10];
    const float* ln2b = (const float*)d_in[11];
    const float* fw1  = (const float*)d_in[12];
    const float* fb1  = (const float*)d_in[13];
    const float* fw2  = (const float*)d_in[14];
    const float* fb2  = (const float*)d_in[15];

    float* ws = (float*)d_ws;
    const size_t U = (size_t)NROWS * DIM;    // 4M floats = 16 MB

    // Arena:
    // U0: lnbf(8MB) + wqkvg(8MB)
    // U1: Vt bf16 (8MB) -> fw1t(8)+fw2t(8)
    // U2: sY fp32 -> h1 low half
    // U3: Vb bf16(8) [dead after vt_cvt] / ybf(8) + wot(2) -> h1 high half
    // U4: sG fp32 -> sXn
    // U5: Qb(8)+Kb(8)
    // U6: sX
    short* lnbf  = (short*)(ws + 0 * U);
    short* wqkvg = lnbf + (size_t)NROWS * DIM;
    short* Vt   = (short*)(ws + 1 * U);
    short* fw1t = (short*)(ws + 1 * U);
    short* fw2t = fw1t + (size_t)DIM * FFN_DIM;
    float* sY  = ws + 2 * U;
    short* h1   = (short*)(ws + 2 * U);              // 32 MB spans U2+U3
    short* Vb   = (short*)(ws + 3 * U);
    short* ybf  = (short*)(ws + 3 * U);
    short* wot  = ybf + (size_t)NROWS * DIM;
    float* sG  = ws + 4 * U;
    float* sXn = ws + 4 * U;                         // after gn_gate, sG dead
    short* Qb   = (short*)(ws + 5 * U);
    short* Kb   = Qb + (size_t)NROWS * DIM;
    float* sX  = ws + 6 * U;

    for (int i = 0; i < 2; ++i) {
        const float* Xin = (i == 0) ? X0 : sX;
        float* Xout = (i == 1) ? (float*)d_out : sX;

        // LN1 -> bf16
        ln_kernel_bf<<<NROWS, 256, 0, stream>>>(Xin, ln1w + i * DIM, ln1b + i * DIM, lnbf);
        // weight transposes into one contiguous (4096,1024) Bt: [Wq|Wk|Wv|WG]
        dim3 tq(HD / 32, DIM / 32, HEADS);
        transpose_cvt<<<tq, 256, 0, stream>>>(Wq + (size_t)i * HEADS * DIM * HD, wqkvg + 0 * DIM * DIM, DIM, HD, (size_t)DIM * HD, (size_t)HD * DIM);
        transpose_cvt<<<tq, 256, 0, stream>>>(Wk + (size_t)i * HEADS * DIM * HD, wqkvg + 1 * DIM * DIM, DIM, HD, (size_t)DIM * HD, (size_t)HD * DIM);
        transpose_cvt<<<tq, 256, 0, stream>>>(Wv + (size_t)i * HEADS * DIM * HD, wqkvg + 2 * DIM * DIM, DIM, HD, (size_t)DIM * HD, (size_t)HD * DIM);
        dim3 tg(DIM / 32, DIM / 32, 1);
        transpose_cvt<<<tg, 256, 0, stream>>>(WG + (size_t)i * DIM * DIM, wqkvg + 3 * (size_t)DIM * DIM, DIM, DIM, 0, 0);
        // fused QKVG projection + xpos + bf16: writes Qb, Kb, Vb, sG
        dim3 gp4(4 * DIM / 128, NROWS / 128);   // (32,32)
        gemm_bf16<4, 32><<<gp4, 256, 0, stream>>>(lnbf, wqkvg, Qb, nullptr, nullptr, Kb, Vb, sG, NROWS, DIM, 4 * DIM);
        // V transpose (bf16 -> bf16 [bh][v][l])
        dim3 vg(DIM / 32, NROWS / 32);
        vt_cvt<<<vg, 256, 0, stream>>>(Vb, Vt);
        // retention -> sY
        dim3 rg(16, 16);
        retention_mfma2<<<rg, 256, 0, stream>>>(Qb, Kb, Vt, sY);
        // groupnorm + gate -> ybf (overwrites Vb region; Vb dead)
        gn_gate_kernel<<<NROWS * HEADS / 4, 256, 0, stream>>>(sY, sG, gnw + i * DIM, gnb + i * DIM, ybf);
        // W_O + residual -> sXn (sG dead)
        transpose_cvt<<<tg, 256, 0, stream>>>(WO + (size_t)i * DIM * DIM, wot, DIM, DIM, 0, 0);
        dim3 gp(DIM / 128, NROWS / 128);   // (8,32)
        gemm_bf16<3, 8><<<gp, 256, 0, stream>>>(ybf, wot, sXn, nullptr, Xin, nullptr, nullptr, nullptr, NROWS, DIM, DIM);
        // LN2 -> lnbf
        ln_kernel_bf<<<NROWS, 256, 0, stream>>>(sXn, ln2w + i * DIM, ln2b + i * DIM, lnbf);
        // FFN weight transposes (U1 free: Vt dead after retention)
        dim3 t1(FFN_DIM / 32, DIM / 32, 1);
        transpose_cvt<<<t1, 256, 0, stream>>>(fw1 + (size_t)i * DIM * FFN_DIM, fw1t, DIM, FFN_DIM, 0, 0);
        dim3 t2(DIM / 32, FFN_DIM / 32, 1);
        transpose_cvt<<<t2, 256, 0, stream>>>(fw2 + (size_t)i * FFN_DIM * DIM, fw2t, FFN_DIM, DIM, 0, 0);
        // FFN1: + bias + gelu -> h1 bf16 (ybf/wot dead after FFN1 reads? no: h1 spans U2+U3,
        //        overwrites ybf region — ybf consumed by W_O gemm, wot consumed there too; safe)
        dim3 gf1(FFN_DIM / 128, NROWS / 128);   // (32,32)
        gemm_bf16<1, 32><<<gf1, 256, 0, stream>>>(lnbf, fw1t, h1, fb1 + i * FFN_DIM, nullptr, nullptr, nullptr, nullptr, NROWS, DIM, FFN_DIM);
        // FFN2: + bias + residual -> Xout fp32
        dim3 gf2(DIM / 128, NROWS / 128);       // (8,32)
        gemm_bf16<2, 8><<<gf2, 256, 0, stream>>>(h1, fw2t, Xout, fb2 + i * DIM, sXn, nullptr, nullptr, nullptr, NROWS, FFN_DIM, DIM);
    }
}

// Round 6
// 838.284 us; speedup vs baseline: 9.3286x; 1.0701x over previous
//
#include <hip/hip_runtime.h>
#include <math.h>

#define DIM 1024
#define FFN_DIM 4096
#define HEADS 8
#define HD 128
#define BB 2
#define LL 2048
#define NROWS (BB*LL)   // 4096

typedef __attribute__((ext_vector_type(8))) short bf16x8;
typedef __attribute__((ext_vector_type(4))) short bf16x4;
typedef __attribute__((ext_vector_type(2))) short bf16x2;
typedef __attribute__((ext_vector_type(4))) float f32x4;

__device__ inline short f2bf(float f) {
    unsigned u = __builtin_bit_cast(unsigned, f);
    unsigned r = (u + 0x7FFFu + ((u >> 16) & 1u)) >> 16;
    return (short)r;
}
__device__ inline float bf2f(short s) {
    unsigned u = ((unsigned)(unsigned short)s) << 16;
    return __builtin_bit_cast(float, u);
}

__device__ __forceinline__ void gl_lds16(const void* g, void* l) {
    __builtin_amdgcn_global_load_lds(
        (const __attribute__((address_space(1))) unsigned int*)g,
        (__attribute__((address_space(3))) unsigned int*)l, 16, 0, 0);
}

// ---------------- LayerNorm (one block per row of 1024) -> bf16 out ----------------
__global__ __launch_bounds__(256) void ln_kernel_bf(
    const float* __restrict__ x, const float* __restrict__ w,
    const float* __restrict__ b, short* __restrict__ out)
{
    int row = blockIdx.x;
    int tid = threadIdx.x;
    const float* xr = x + (size_t)row * DIM;
    float4 v = *(const float4*)(xr + tid * 4);
    float s  = v.x + v.y + v.z + v.w;
    float ss = v.x*v.x + v.y*v.y + v.z*v.z + v.w*v.w;
    #pragma unroll
    for (int o = 32; o > 0; o >>= 1) { s += __shfl_down(s, o); ss += __shfl_down(ss, o); }
    __shared__ float red[10];
    int wid = tid >> 6;
    if ((tid & 63) == 0) { red[wid] = s; red[4 + wid] = ss; }
    __syncthreads();
    if (tid == 0) {
        float t  = red[0] + red[1] + red[2] + red[3];
        float t2 = red[4] + red[5] + red[6] + red[7];
        float mu  = t * (1.f / DIM);
        float var = t2 * (1.f / DIM) - mu * mu;
        red[8] = mu; red[9] = rsqrtf(var + 1e-5f);
    }
    __syncthreads();
    float mu = red[8], rs = red[9];
    float4 wv = *(const float4*)(w + tid * 4);
    float4 bv = *(const float4*)(b + tid * 4);
    bf16x4 o;
    o[0] = f2bf((v.x - mu) * rs * wv.x + bv.x);
    o[1] = f2bf((v.y - mu) * rs * wv.y + bv.y);
    o[2] = f2bf((v.z - mu) * rs * wv.z + bv.z);
    o[3] = f2bf((v.w - mu) * rs * wv.w + bv.w);
    *(bf16x4*)(out + (size_t)row * DIM + tid * 4) = o;
}

// ---------------- generic fp32(R,C) -> bf16 transpose (C,R), batched ----------------
__global__ __launch_bounds__(256) void transpose_cvt(
    const float* __restrict__ in, short* __restrict__ out,
    int R, int C, size_t ibs, size_t obs)
{
    __shared__ float t[32][33];
    int bz = blockIdx.z;
    int r0 = blockIdx.y * 32, c0 = blockIdx.x * 32;
    int tx = threadIdx.x & 31, ty = threadIdx.x >> 5;   // ty 0..7
    const float* ip = in + (size_t)bz * ibs;
    short* op = out + (size_t)bz * obs;
    #pragma unroll
    for (int i = 0; i < 4; ++i)
        t[ty + i * 8][tx] = ip[(size_t)(r0 + ty + i * 8) * C + c0 + tx];
    __syncthreads();
    #pragma unroll
    for (int i = 0; i < 4; ++i)
        op[(size_t)(c0 + ty + i * 8) * R + r0 + tx] = f2bf(t[tx][ty + i * 8]);
}

// ---------------- Vb bf16 (NROWS,DIM) -> Vt bf16 [bh][v][l] ----------------
__global__ __launch_bounds__(256) void vt_cvt(
    const short* __restrict__ Vb, short* __restrict__ Vt)
{
    __shared__ short t[32][34];
    int r0 = blockIdx.y * 32, c0 = blockIdx.x * 32;   // r: global row (b*LL+l), c: h*HD+v
    int tx = threadIdx.x & 31, ty = threadIdx.x >> 5;
    #pragma unroll
    for (int i = 0; i < 4; ++i)
        t[ty + i * 8][tx] = Vb[(size_t)(r0 + ty + i * 8) * DIM + c0 + tx];
    __syncthreads();
    int b = r0 >> 11;
    int l = (r0 & (LL - 1));
    #pragma unroll
    for (int i = 0; i < 4; ++i) {
        int c = c0 + ty + i * 8;
        int h = c >> 7, v = c & 127;
        Vt[(((size_t)(b * HEADS + h) * HD + v) << 11) + l + tx] = t[tx][ty + i * 8];
    }
}

// ---------------- bf16 MFMA GEMM: C = A(N,K) @ Bt(M,K)^T ----------------
// Double-buffered single-barrier K-loop (retention-style): loads for tile k+1
// issue right after the barrier that drained tile k -> one full iteration of
// compute hides the staging latency. EPI: 0 plain fp32, 1 bias+gelu->bf16,
// 2 bias+residual fp32, 3 residual fp32,
// 4 QKVG: Q->rotary->bf16 P0, K->rotary(down)->bf16 P1, V->bf16 P2, G->bf16 P3
template<int EPI, int GX>
__global__ __launch_bounds__(256) void gemm_bf16(
    const short* __restrict__ A, const short* __restrict__ Bt,
    void* __restrict__ Cv, const float* __restrict__ bias,
    const float* __restrict__ R_,
    void* __restrict__ P1, void* __restrict__ P2, void* __restrict__ P3,
    int N, int K, int M)
{
    __shared__ __align__(16) short As[2][128 * 32];   // 8 KB each
    __shared__ __align__(16) short Bs[2][128 * 32];
    int tid = threadIdx.x;
    int w = tid >> 6, lane = tid & 63;
    int q = lane >> 4, lr = lane & 15;
    int wr = w >> 1, wc = w & 1;

    // XCD-aware tile remap: blocks with id%8==k form XCD k's compact region.
    int id = blockIdx.y * GX + blockIdx.x;
    int xcd = id & 7, j = id >> 3;
    constexpr int rx_n = (GX >= 8) ? GX / 8 : 1;
    int tp = (GX * gridDim.y) >> 3;              // tiles per xcd
    int rh = tp >> 3;                            // region height (rw = 8)
    int lbx = j & 7, lby = j >> 3;
    int rx = xcd % rx_n, ry = xcd / rx_n;
    int bm = (ry * rh + lby) * 128;
    int bn = (rx * 8 + lbx) * 128;

    int srow = lane >> 2;
    int sseg = lane & 3;

    f32x4 acc[4][4];
    #pragma unroll
    for (int mi = 0; mi < 4; ++mi)
        #pragma unroll
        for (int ni = 0; ni < 4; ++ni) acc[mi][ni] = (f32x4){0.f, 0.f, 0.f, 0.f};

    // prologue: stage k-tile 0 into buf 0
    #pragma unroll
    for (int i = 0; i < 2; ++i) {
        int jj = w * 2 + i;
        int row = jj * 16 + srow;
        int cseg = sseg ^ ((row >> 1) & 3);
        gl_lds16(A  + (size_t)(bm + row) * K + cseg * 8, &As[0][jj * 16 * 32]);
        gl_lds16(Bt + (size_t)(bn + row) * K + cseg * 8, &Bs[0][jj * 16 * 32]);
    }

    int nk = K >> 5;
    for (int kt = 0; kt < nk; ++kt) {
        int cur = kt & 1;
        __syncthreads();    // drains buf[cur] staging (vmcnt0) + protects buf reuse
        if (kt + 1 < nk) {
            int k1 = (kt + 1) << 5;
            #pragma unroll
            for (int i = 0; i < 2; ++i) {
                int jj = w * 2 + i;
                int row = jj * 16 + srow;
                int cseg = sseg ^ ((row >> 1) & 3);
                gl_lds16(A  + (size_t)(bm + row) * K + k1 + cseg * 8, &As[cur ^ 1][jj * 16 * 32]);
                gl_lds16(Bt + (size_t)(bn + row) * K + k1 + cseg * 8, &Bs[cur ^ 1][jj * 16 * 32]);
            }
        }
        bf16x8 af[4], bfr[4];
        #pragma unroll
        for (int mi = 0; mi < 4; ++mi) {
            int row = wr * 64 + mi * 16 + lr;
            af[mi] = *(const bf16x8*)&As[cur][row * 32 + (q ^ ((row >> 1) & 3)) * 8];
        }
        #pragma unroll
        for (int ni = 0; ni < 4; ++ni) {
            int row = wc * 64 + ni * 16 + lr;
            bfr[ni] = *(const bf16x8*)&Bs[cur][row * 32 + (q ^ ((row >> 1) & 3)) * 8];
        }
        #pragma unroll
        for (int mi = 0; mi < 4; ++mi)
            #pragma unroll
            for (int ni = 0; ni < 4; ++ni)
                acc[mi][ni] = __builtin_amdgcn_mfma_f32_16x16x32_bf16(af[mi], bfr[ni], acc[mi][ni], 0, 0, 0);
    }

    if constexpr (EPI == 4) {
        // quarters of M=4096: 0=Q(rotary up), 1=K(rotary down), 2=V(bf16), 3=G(bf16)
        int sel = bn >> 10;                    // block-uniform
        int row_base = bm + wr * 64 + q * 4;   // +mi*16+r
        int l0 = row_base & (LL - 1);          // same b for whole block
        #pragma unroll
        for (int ni = 0; ni < 4; ++ni) {
            int col = bn + wc * 64 + ni * 16 + lr;
            int cq = col & (DIM - 1);
            if (sel <= 1) {
                int jj = (col & 127) >> 1;
                float lb = log2f((2.f * jj + 51.2f) / 179.2f);
                if (sel == 1) lb = -lb;        // downscale for K
                float invf = exp2f(-(float)jj * (13.287712379549449f / 64.f));
                float snb, cnb;
                sincosf((float)l0 * invf, &snb, &cnb);
                float scb = exp2f(lb * (float)l0 * (1.f / 512.f));
                float s1, c1, s16, c16;
                __sincosf(invf, &s1, &c1);
                __sincosf(16.f * invf, &s16, &c16);
                float st1 = exp2f(lb * (1.f / 512.f));
                float st16 = exp2f(lb * (16.f / 512.f));
                short* Ob = (short*)(sel == 0 ? Cv : P1);
                #pragma unroll
                for (int mi = 0; mi < 4; ++mi) {
                    float cr = cnb, sr = snb, sv = scb;
                    #pragma unroll
                    for (int r = 0; r < 4; ++r) {
                        float cs = cr * sv, ssn = sr * sv;
                        float v = acc[mi][ni][r];
                        float p = __shfl_xor(v, 1);
                        float o = (lr & 1) ? (v * cs + p * ssn) : (v * cs - p * ssn);
                        Ob[(size_t)(row_base + mi * 16 + r) * DIM + cq] = f2bf(o);
                        if (r < 3) {
                            float crn = cr * c1 - sr * s1;
                            sr = sr * c1 + cr * s1; cr = crn;
                            sv *= st1;
                        }
                    }
                    float cbn = cnb * c16 - snb * s16;
                    snb = snb * c16 + cnb * s16; cnb = cbn;
                    scb *= st16;
                }
            } else if (sel == 2) {
                short* Vb = (short*)P2;
                #pragma unroll
                for (int mi = 0; mi < 4; ++mi)
                    #pragma unroll
                    for (int r = 0; r < 4; ++r)
                        Vb[(size_t)(row_base + mi * 16 + r) * DIM + cq] = f2bf(acc[mi][ni][r]);
            } else {
                short* Gb = (short*)P3;
                #pragma unroll
                for (int mi = 0; mi < 4; ++mi)
                    #pragma unroll
                    for (int r = 0; r < 4; ++r)
                        Gb[(size_t)(row_base + mi * 16 + r) * DIM + cq] = f2bf(acc[mi][ni][r]);
            }
        }
        return;
    }

    float* Cf = (float*)Cv;
    short* Cs = (short*)Cv;
    #pragma unroll
    for (int ni = 0; ni < 4; ++ni) {
        int col = bn + wc * 64 + ni * 16 + lr;
        float bi = 0.f;
        if constexpr (EPI == 1 || EPI == 2) bi = bias[col];
        #pragma unroll
        for (int mi = 0; mi < 4; ++mi) {
            int row0 = bm + wr * 64 + mi * 16 + q * 4;
            #pragma unroll
            for (int r = 0; r < 4; ++r) {
                size_t off = (size_t)(row0 + r) * M + col;
                float v = acc[mi][ni][r];
                if constexpr (EPI == 1) {
                    v += bi;
                    v = 0.5f * v * (1.f + erff(v * 0.70710678118654752f));
                    Cs[off] = f2bf(v);
                } else if constexpr (EPI == 2) {
                    Cf[off] = v + bi + R_[off];
                } else if constexpr (EPI == 3) {
                    Cf[off] = v + R_[off];
                } else {
                    Cf[off] = v;
                }
            }
        }
    }
}

// ---------------- retention: bf16 inputs, global_load_lds staging, dbuf ----------------
#define PSTR 40
__global__ __launch_bounds__(256) void retention_mfma2(
    const short* __restrict__ Qb, const short* __restrict__ Kb,
    const short* __restrict__ Vt, float* __restrict__ Y)
{
    __shared__ __align__(16) short Ks[2][32 * 128];
    __shared__ __align__(16) short Vs[2][128 * 32];
    __shared__ __align__(16) short Ps[4][16 * PSTR];
    int tid = threadIdx.x;
    int w = tid >> 6, lane = tid & 63;
    int q = lane >> 4, lr = lane & 15;
    int bh = blockIdx.x;
    int b = bh >> 3, h = bh & 7;
    size_t bL = (size_t)b * LL;
    const short* Kbh = Kb + (bL << 10) + (h << 7);
    const short* Qbh = Qb + (bL << 10) + (h << 7);
    const short* Vbh = Vt + ((size_t)bh << 18);
    float* Ybh = Y + (bL << 10) + (h << 7);

    const float lg_lo = -3.4657359027997265f;
    const float lg_hi = -6.2383246250395075f;
    float gamma = 1.f - expf(lg_lo + (lg_hi - lg_lo) * ((float)h / 7.f));
    float logg = logf(gamma);
    float gm32 = expf(-32.f * logg);
    float rf[4];
    #pragma unroll
    for (int r = 0; r < 4; ++r) rf[r] = expf(logg * (float)(q * 4 + r));
    float cf0 = expf(-logg * (float)lr);
    float cf1 = expf(-logg * (float)(16 + lr));
    int dqlr = q * 4 - lr;

    int krow = lane >> 4;
    int kslot = lane & 15;
    int vrow = lane >> 2;
    int vslot = lane & 3;

    #pragma unroll 1
    for (int pass = 0; pass < 2; ++pass) {
        int jt = pass ? (31 - blockIdx.y) : blockIdx.y;
        int l0w = jt * 64 + w * 16;
        int ntiles = 2 * jt + 2;

        bf16x8 qf[4];
        {
            const short* qp = Qbh + ((size_t)(l0w + lr) << 10) + q * 8;
            #pragma unroll
            for (int es = 0; es < 4; ++es) qf[es] = *(const bf16x8*)(qp + es * 32);
        }
        f32x4 yacc[8];
        #pragma unroll
        for (int vt = 0; vt < 8; ++vt) yacc[vt] = (f32x4){0.f, 0.f, 0.f, 0.f};
        float tf = expf(logg * (float)l0w);

        #pragma unroll
        for (int i = 0; i < 2; ++i) {
            int kr = w * 8 + i * 4 + krow;
            gl_lds16(Kbh + ((size_t)kr << 10) + ((kslot ^ (kr & 15)) << 3),
                     &Ks[0][(w * 8 + i * 4) * 128]);
            int vr = w * 32 + i * 16 + vrow;
            gl_lds16(Vbh + ((size_t)vr << 11) + ((vslot ^ (vr & 3)) << 3),
                     &Vs[0][(w * 32 + i * 16) * 32]);
        }

        #pragma unroll 1
        for (int mt = 0; mt < ntiles; ++mt) {
            int cur = mt & 1;
            int m0 = mt * 32;
            __syncthreads();
            if (mt + 1 < ntiles) {
                int m1 = m0 + 32;
                #pragma unroll
                for (int i = 0; i < 2; ++i) {
                    int kr = w * 8 + i * 4 + krow;
                    gl_lds16(Kbh + ((size_t)(m1 + kr) << 10) + ((kslot ^ (kr & 15)) << 3),
                             &Ks[cur ^ 1][(w * 8 + i * 4) * 128]);
                    int vr = w * 32 + i * 16 + vrow;
                    gl_lds16(Vbh + ((size_t)vr << 11) + m1 + ((vslot ^ (vr & 3)) << 3),
                             &Vs[cur ^ 1][(w * 32 + i * 16) * 32]);
                }
            }
            if (m0 <= l0w + 15) {
                int dt = l0w - m0;
                f32x4 sa0 = (f32x4){0.f,0.f,0.f,0.f};
                f32x4 sa1 = (f32x4){0.f,0.f,0.f,0.f};
                #pragma unroll
                for (int es = 0; es < 4; ++es) {
                    int slot = ((es * 4 + q) ^ lr) * 8;
                    bf16x8 bk0 = *(const bf16x8*)&Ks[cur][lr * 128 + slot];
                    bf16x8 bk1 = *(const bf16x8*)&Ks[cur][(16 + lr) * 128 + slot];
                    sa0 = __builtin_amdgcn_mfma_f32_16x16x32_bf16(qf[es], bk0, sa0, 0, 0, 0);
                    sa1 = __builtin_amdgcn_mfma_f32_16x16x32_bf16(qf[es], bk1, sa1, 0, 0, 0);
                }
                #pragma unroll
                for (int r = 0; r < 4; ++r) {
                    float p0 = sa0[r] * (rf[r] * cf0 * tf);
                    float p1 = sa1[r] * (rf[r] * cf1 * tf);
                    int d0 = dt + dqlr + r;
                    Ps[w][(q*4 + r) * PSTR + lr]      = (d0 >= 0)      ? f2bf(p0) : (short)0;
                    Ps[w][(q*4 + r) * PSTR + 16 + lr] = (d0 - 16 >= 0) ? f2bf(p1) : (short)0;
                }
                bf16x8 pa = *(const bf16x8*)&Ps[w][lr * PSTR + q * 8];
                int vslot_r = (q ^ (lr & 3)) * 8;
                #pragma unroll
                for (int vt = 0; vt < 8; ++vt) {
                    bf16x8 bv = *(const bf16x8*)&Vs[cur][(vt * 16 + lr) * 32 + vslot_r];
                    yacc[vt] = __builtin_amdgcn_mfma_f32_16x16x32_bf16(pa, bv, yacc[vt], 0, 0, 0);
                }
            }
            tf *= gm32;
        }
        __syncthreads();
        float* yp = Ybh + ((size_t)(l0w + q * 4) << 10) + lr;
        #pragma unroll
        for (int vt = 0; vt < 8; ++vt)
            #pragma unroll
            for (int r = 0; r < 4; ++r)
                yp[((size_t)r << 10) + vt * 16] = yacc[vt][r];
    }
}

// ---------------- groupnorm * swish-gate (bf16 G) -> bf16 out ----------------
__global__ __launch_bounds__(256) void gn_gate_kernel(
    const float* __restrict__ Y, const short* __restrict__ Gb,
    const float* __restrict__ w, const float* __restrict__ b,
    short* __restrict__ ybf)
{
    int tid = threadIdx.x;
    int wid = tid >> 6, lane = tid & 63;
    int grp = blockIdx.x * 4 + wid;
    int n = grp >> 3, h = grp & 7;
    size_t base = (size_t)n * DIM + h * HD + lane * 2;
    float2 y = *(const float2*)(Y + base);
    float s = y.x + y.y, ss = y.x * y.x + y.y * y.y;
    #pragma unroll
    for (int o = 32; o > 0; o >>= 1) { s += __shfl_down(s, o); ss += __shfl_down(ss, o); }
    s = __shfl(s, 0); ss = __shfl(ss, 0);
    float mu  = s * (1.f / HD);
    float var = ss * (1.f / HD) - mu * mu;
    float rs  = rsqrtf(var + 1e-5f);
    float2 wv = *(const float2*)(w + h * HD + lane * 2);
    float2 bv = *(const float2*)(b + h * HD + lane * 2);
    bf16x2 gv = *(const bf16x2*)(Gb + base);
    float gx = bf2f(gv[0]), gy = bf2f(gv[1]);
    float g0 = gx / (1.f + expf(-gx));
    float g1 = gy / (1.f + expf(-gy));
    bf16x2 o;
    o[0] = f2bf(((y.x - mu) * rs * wv.x + bv.x) * g0);
    o[1] = f2bf(((y.y - mu) * rs * wv.y + bv.y) * g1);
    *(bf16x2*)(ybf + base) = o;
}

extern "C" void kernel_launch(void* const* d_in, const int* in_sizes, int n_in,
                              void* d_out, int out_size, void* d_ws, size_t ws_size,
                              hipStream_t stream)
{
    const float* X0   = (const float*)d_in[0];
    const float* Wq   = (const float*)d_in[1];
    const float* Wk   = (const float*)d_in[2];
    const float* Wv   = (const float*)d_in[3];
    const float* WG   = (const float*)d_in[4];
    const float* WO   = (const float*)d_in[5];
    const float* gnw  = (const float*)d_in[6];
    const float* gnb  = (const float*)d_in[7];
    const float* ln1w = (const float*)d_in[8];
    const float* ln1b = (const float*)d_in[9];
    const float* ln2w = (const float*)d_in[10];
    const float* ln2b = (const float*)d_in[11];
    const float* fw1  = (const float*)d_in[12];
    const float* fb1  = (const float*)d_in[13];
    const float* fw2  = (const float*)d_in[14];
    const float* fb2  = (const float*)d_in[15];

    float* ws = (float*)d_ws;
    const size_t U = (size_t)NROWS * DIM;    // 4M floats = 16 MB

    // Arena:
    // U0: lnbf(8MB) + wqkvg(8MB)
    // U1: Vt bf16 (8MB) -> fw1t(8)+fw2t(8)
    // U2: sY fp32 -> h1 low half
    // U3: Vb bf16(8) [dead after vt_cvt] / ybf(8) + wot(2) -> h1 high half
    // U4: Gb bf16(8) -> sXn fp32(16)
    // U5: Qb(8)+Kb(8)
    // U6: sX
    short* lnbf  = (short*)(ws + 0 * U);
    short* wqkvg = lnbf + (size_t)NROWS * DIM;
    short* Vt   = (short*)(ws + 1 * U);
    short* fw1t = (short*)(ws + 1 * U);
    short* fw2t = fw1t + (size_t)DIM * FFN_DIM;
    float* sY  = ws + 2 * U;
    short* h1   = (short*)(ws + 2 * U);              // 32 MB spans U2+U3
    short* Vb   = (short*)(ws + 3 * U);
    short* ybf  = (short*)(ws + 3 * U);
    short* wot  = ybf + (size_t)NROWS * DIM;
    short* Gb   = (short*)(ws + 4 * U);
    float* sXn = ws + 4 * U;                         // after gn_gate, Gb dead
    short* Qb   = (short*)(ws + 5 * U);
    short* Kb   = Qb + (size_t)NROWS * DIM;
    float* sX  = ws + 6 * U;

    for (int i = 0; i < 2; ++i) {
        const float* Xin = (i == 0) ? X0 : sX;
        float* Xout = (i == 1) ? (float*)d_out : sX;

        // LN1 -> bf16
        ln_kernel_bf<<<NROWS, 256, 0, stream>>>(Xin, ln1w + i * DIM, ln1b + i * DIM, lnbf);
        // weight transposes into one contiguous (4096,1024) Bt: [Wq|Wk|Wv|WG]
        dim3 tq(HD / 32, DIM / 32, HEADS);
        transpose_cvt<<<tq, 256, 0, stream>>>(Wq + (size_t)i * HEADS * DIM * HD, wqkvg + 0 * DIM * DIM, DIM, HD, (size_t)DIM * HD, (size_t)HD * DIM);
        transpose_cvt<<<tq, 256, 0, stream>>>(Wk + (size_t)i * HEADS * DIM * HD, wqkvg + 1 * DIM * DIM, DIM, HD, (size_t)DIM * HD, (size_t)HD * DIM);
        transpose_cvt<<<tq, 256, 0, stream>>>(Wv + (size_t)i * HEADS * DIM * HD, wqkvg + 2 * DIM * DIM, DIM, HD, (size_t)DIM * HD, (size_t)HD * DIM);
        dim3 tg(DIM / 32, DIM / 32, 1);
        transpose_cvt<<<tg, 256, 0, stream>>>(WG + (size_t)i * DIM * DIM, wqkvg + 3 * (size_t)DIM * DIM, DIM, DIM, 0, 0);
        // fused QKVG projection + xpos + bf16: writes Qb, Kb, Vb, Gb
        dim3 gp4(4 * DIM / 128, NROWS / 128);   // (32,32)
        gemm_bf16<4, 32><<<gp4, 256, 0, stream>>>(lnbf, wqkvg, Qb, nullptr, nullptr, Kb, Vb, Gb, NROWS, DIM, 4 * DIM);
        // V transpose (bf16 -> bf16 [bh][v][l])
        dim3 vg(DIM / 32, NROWS / 32);
        vt_cvt<<<vg, 256, 0, stream>>>(Vb, Vt);
        // retention -> sY
        dim3 rg(16, 16);
        retention_mfma2<<<rg, 256, 0, stream>>>(Qb, Kb, Vt, sY);
        // groupnorm + gate -> ybf (overwrites Vb region; Vb dead)
        gn_gate_kernel<<<NROWS * HEADS / 4, 256, 0, stream>>>(sY, Gb, gnw + i * DIM, gnb + i * DIM, ybf);
        // W_O + residual -> sXn (Gb dead)
        transpose_cvt<<<tg, 256, 0, stream>>>(WO + (size_t)i * DIM * DIM, wot, DIM, DIM, 0, 0);
        dim3 gp(DIM / 128, NROWS / 128);   // (8,32)
        gemm_bf16<3, 8><<<gp, 256, 0, stream>>>(ybf, wot, sXn, nullptr, Xin, nullptr, nullptr, nullptr, NROWS, DIM, DIM);
        // LN2 -> lnbf
        ln_kernel_bf<<<NROWS, 256, 0, stream>>>(sXn, ln2w + i * DIM, ln2b + i * DIM, lnbf);
        // FFN weight transposes (U1 free: Vt dead after retention)
        dim3 t1(FFN_DIM / 32, DIM / 32, 1);
        transpose_cvt<<<t1, 256, 0, stream>>>(fw1 + (size_t)i * DIM * FFN_DIM, fw1t, DIM, FFN_DIM, 0, 0);
        dim3 t2(DIM / 32, FFN_DIM / 32, 1);
        transpose_cvt<<<t2, 256, 0, stream>>>(fw2 + (size_t)i * FFN_DIM * DIM, fw2t, FFN_DIM, DIM, 0, 0);
        // FFN1: + bias + gelu -> h1 bf16
        dim3 gf1(FFN_DIM / 128, NROWS / 128);   // (32,32)
        gemm_bf16<1, 32><<<gf1, 256, 0, stream>>>(lnbf, fw1t, h1, fb1 + i * FFN_DIM, nullptr, nullptr, nullptr, nullptr, NROWS, DIM, FFN_DIM);
        // FFN2: + bias + residual -> Xout fp32
        dim3 gf2(DIM / 128, NROWS / 128);       // (8,32)
        gemm_bf16<2, 8><<<gf2, 256, 0, stream>>>(h1, fw2t, Xout, fb2 + i * DIM, sXn, nullptr, nullptr, nullptr, NROWS, FFN_DIM, DIM);
    }
}